// Round 1
// baseline (576.903 us; speedup 1.0000x reference)
//
#include <hip/hip_runtime.h>
#include <stdint.h>

#define B_ 8
#define N_ 32768
#define S1_ 512
#define S2_ 128

// ---------------- workspace layout (bytes) ----------------
#define OFF_XR4   ((size_t)0)        // B*N float4 (xyz, rr)          4194304
#define OFF_C1    ((size_t)4194304)  // B*512*3 f32                     49152
#define OFF_C1R4  ((size_t)4243456)  // B*512 float4                    65536
#define OFF_C2    ((size_t)4308992)  // B*128*3 f32                     12288
#define OFF_NIDX1 ((size_t)4321280)  // B*512*32 i32                   524288
#define OFF_F1    ((size_t)4845568)  // B*512*64 f32                   524288
#define OFF_NIDX2 ((size_t)5369856)  // B*128*32 i32                   131072
#define OFF_F2    ((size_t)5500928)  // B*128*128 f32                  524288
#define OFF_G1    ((size_t)6025216)  // B*512*64 f32                   524288
// total ~6.25 MB

struct Samps { int s1[S1_]; int s2[S2_]; };

// ================= host: replicate np.random.default_rng(0) =================
typedef unsigned __int128 u128;
struct RngState { u128 state, inc; bool has32; uint32_t saved; };

static uint64_t rng_next64(RngState* r) {
  const u128 MULT = ((u128)0x2360ed051fc65da4ULL << 64) | 0x4385df649fccf645ULL;
  r->state = r->state * MULT + r->inc;
  uint64_t hi = (uint64_t)(r->state >> 64), lo = (uint64_t)r->state;
  uint64_t xs = hi ^ lo;
  unsigned rot = (unsigned)(r->state >> 122);
  return (xs >> rot) | (xs << ((64u - rot) & 63u));
}
static uint32_t rng_next32(RngState* r) {
  if (r->has32) { r->has32 = false; return r->saved; }
  uint64_t v = rng_next64(r);
  r->has32 = true; r->saved = (uint32_t)(v >> 32);
  return (uint32_t)v;
}
static uint32_t rng_interval(RngState* r, uint32_t mx) {
  if (mx == 0) return 0;
  uint32_t mask = mx;
  mask |= mask >> 1; mask |= mask >> 2; mask |= mask >> 4;
  mask |= mask >> 8; mask |= mask >> 16;
  uint32_t v;
  while ((v = (rng_next32(r) & mask)) > mx) {}
  return v;
}
static void compute_samples(int* s1, int* s2) {
  // SeedSequence(0), pool_size=4
  uint32_t pool[4];
  uint32_t hc = 0x43b0d7e5u;
  auto hmix = [&hc](uint32_t v) -> uint32_t {
    v ^= hc; hc *= 0x931e8875u; v *= hc; v ^= v >> 16; return v;
  };
  auto mixf = [](uint32_t x, uint32_t y) -> uint32_t {
    uint32_t rr = (x * 0xca01f9ddu) ^ (y * 0x4973f715u);
    rr ^= rr >> 16; return rr;
  };
  pool[0] = hmix(0u); pool[1] = hmix(0u); pool[2] = hmix(0u); pool[3] = hmix(0u);
  for (int s = 0; s < 4; ++s)
    for (int d = 0; d < 4; ++d)
      if (s != d) pool[d] = mixf(pool[d], hmix(pool[s]));
  uint32_t hc2 = 0x8b51f9ddu;
  uint32_t w32[8];
  for (int i = 0; i < 8; ++i) {
    uint32_t dv = pool[i & 3];
    dv ^= hc2; hc2 *= 0x58f38dedu; dv *= hc2; dv ^= dv >> 16;
    w32[i] = dv;
  }
  uint64_t w64[4];
  for (int i = 0; i < 4; ++i) w64[i] = (uint64_t)w32[2*i] | ((uint64_t)w32[2*i+1] << 32);
  const u128 MULT = ((u128)0x2360ed051fc65da4ULL << 64) | 0x4385df649fccf645ULL;
  u128 initstate = ((u128)w64[0] << 64) | w64[1];
  u128 initseq   = ((u128)w64[2] << 64) | w64[3];
  RngState r; r.has32 = false; r.saved = 0;
  r.inc = (initseq << 1) | 1;
  r.state = 0;
  r.state = r.state * MULT + r.inc;
  r.state += initstate;
  r.state = r.state * MULT + r.inc;
  static int perm1[N_];
  for (int i = 0; i < N_; ++i) perm1[i] = i;
  for (int i = N_ - 1; i > 0; --i) {
    uint32_t j = rng_interval(&r, (uint32_t)i);
    int t = perm1[i]; perm1[i] = perm1[j]; perm1[j] = t;
  }
  for (int i = 0; i < S1_; ++i) s1[i] = perm1[i];
  int perm2[S1_];
  for (int i = 0; i < S1_; ++i) perm2[i] = i;
  for (int i = S1_ - 1; i > 0; --i) {
    uint32_t j = rng_interval(&r, (uint32_t)i);
    int t = perm2[i]; perm2[i] = perm2[j]; perm2[j] = t;
  }
  for (int i = 0; i < S2_; ++i) s2[i] = perm2[i];
}

// ================= device =================

__global__ void k_prep(const float* __restrict__ x, float4* __restrict__ xr4) {
  int t = blockIdx.x * blockDim.x + threadIdx.x;   // < B*N exactly
  float a = x[3*t], b = x[3*t+1], c = x[3*t+2];
  xr4[t] = make_float4(a, b, c, a*a + b*b + c*c);
}

__global__ void k_centers(const float* __restrict__ x, Samps sm,
                          float* __restrict__ c1, float4* __restrict__ c1r4,
                          float* __restrict__ c2) {
  int t = blockIdx.x * blockDim.x + threadIdx.x;
  if (t < B_*S1_) {
    int b = t >> 9, c = t & (S1_-1);
    int sidx = sm.s1[c];
    const float* src = x + ((size_t)b*N_ + sidx)*3;
    float a = src[0], bb = src[1], cc = src[2];
    c1[(size_t)t*3+0] = a; c1[(size_t)t*3+1] = bb; c1[(size_t)t*3+2] = cc;
    c1r4[t] = make_float4(a, bb, cc, a*a + bb*bb + cc*cc);
  } else {
    int u = t - B_*S1_;
    if (u < B_*S2_) {
      int b = u >> 7, c = u & (S2_-1);
      int sidx = sm.s1[sm.s2[c]];
      const float* src = x + ((size_t)b*N_ + sidx)*3;
      c2[(size_t)u*3+0] = src[0]; c2[(size_t)u*3+1] = src[1]; c2[(size_t)u*3+2] = src[2];
    }
  }
}

// ---- kNN: one wave per query, wave-distributed sorted top-64 (packed u64 keys) ----
__device__ __forceinline__ void knn_flush(unsigned long long& lst, unsigned long long& qk,
                                          bool& qfull, unsigned long long& T, int lane) {
  unsigned long long bk = qfull ? qk : ~0ULL;
  qfull = false;
  // bitonic sort 64 keys across lanes, ascending
  #pragma unroll
  for (int k = 2; k <= 64; k <<= 1) {
    #pragma unroll
    for (int j = k >> 1; j >= 1; j >>= 1) {
      unsigned long long o = __shfl_xor(bk, j);
      bool keepmin = (((lane & j) == 0) == ((lane & k) == 0));
      bool less = (o < bk);
      if (less == keepmin) bk = o;
    }
  }
  // merge sorted lst with sorted bk: keep lowest 64
  unsigned long long rev = __shfl(bk, 63 - lane);
  unsigned long long v = (lst < rev) ? lst : rev;
  #pragma unroll
  for (int j = 32; j >= 1; j >>= 1) {
    unsigned long long o = __shfl_xor(v, j);
    bool keepmin = ((lane & j) == 0);
    bool less = (o < v);
    if (less == keepmin) v = o;
  }
  lst = v;
  T = __shfl(v, 31);   // true running 32nd-smallest => tight, valid reject bound
}

__launch_bounds__(256)
__global__ void k_knn(const float4* __restrict__ refs4, const float* __restrict__ qpts,
                      int* __restrict__ out_idx, int nrefs, int qshift) {
  const int tid = threadIdx.x, wave = tid >> 6, lane = tid & 63;
  const int q = blockIdx.x * 4 + wave;
  const int b = q >> qshift;
  const float4* refs = refs4 + (size_t)b * nrefs;
  float qx = qpts[(size_t)q*3+0], qy = qpts[(size_t)q*3+1], qz = qpts[(size_t)q*3+2];
  float qq = qx*qx + qy*qy + qz*qz;
  unsigned long long lst = ~0ULL, qk = ~0ULL, T = ~0ULL;
  bool qfull = false;
  for (int p = lane; p < nrefs; p += 64) {
    float4 rv = refs[p];
    float dot = qx*rv.x + qy*rv.y + qz*rv.z;
    float d = (qq - 2.0f*dot) + rv.w;     // same formula as reference
    unsigned int ub = __float_as_uint(d);
    ub ^= ((unsigned int)((int)ub >> 31)) | 0x80000000u;   // order-preserving map
    unsigned long long key = ((unsigned long long)ub << 32) | (unsigned int)p;
    bool cand = (key < T);
    if (__any(cand && qfull) || __popcll(__ballot(qfull)) >= 24) {
      knn_flush(lst, qk, qfull, T, lane);
      cand = (key < T);
    }
    if (cand) { qk = key; qfull = true; }
  }
  if (__any(qfull)) knn_flush(lst, qk, qfull, T, lane);
  if (lane < 32) out_idx[(size_t)q*32 + lane] = (int)(lst & 0xffffffffu);
}

// ---- SA1 MLP (3->64 relu ->64) + max over 32 neighbors; wave per center ----
__launch_bounds__(256)
__global__ void k_sa1mlp(const float* __restrict__ x, const int* __restrict__ nidx1,
                         const float* __restrict__ w1, const float* __restrict__ b1,
                         const float* __restrict__ w2, const float* __restrict__ b2,
                         float* __restrict__ f1) {
  __shared__ __align__(16) float hbuf[4][64];
  const int tid = threadIdx.x, wave = tid >> 6, lane = tid & 63;
  const int q = blockIdx.x * 4 + wave;
  const int b = q >> 9;
  const float* xb = x + (size_t)b * N_ * 3;
  float wc0 = w1[lane], wc1 = w1[64 + lane], wc2 = w1[128 + lane];
  float b1v = b1[lane], b2v = b2[lane];
  float w2c[64];
  #pragma unroll
  for (int h = 0; h < 64; ++h) w2c[h] = w2[h*64 + lane];
  const int* nb = nidx1 + (size_t)q * 32;
  float fm = -3.402823466e+38f;
  for (int j = 0; j < 32; ++j) {
    int n = nb[j];
    float px = xb[3*n], py = xb[3*n+1], pz = xb[3*n+2];
    float h1 = fmaf(px, wc0, fmaf(py, wc1, fmaf(pz, wc2, b1v)));
    h1 = fmaxf(h1, 0.0f);
    __syncthreads();
    hbuf[wave][lane] = h1;
    __syncthreads();
    float acc = b2v;
    const float4* hv = (const float4*)(&hbuf[wave][0]);
    #pragma unroll
    for (int h4 = 0; h4 < 16; ++h4) {
      float4 v = hv[h4];
      acc = fmaf(v.x, w2c[4*h4+0], acc);
      acc = fmaf(v.y, w2c[4*h4+1], acc);
      acc = fmaf(v.z, w2c[4*h4+2], acc);
      acc = fmaf(v.w, w2c[4*h4+3], acc);
    }
    fm = fmaxf(fm, acc);
  }
  f1[(size_t)q*64 + lane] = fm;
}

// ---- SA2 MLP (64->128 relu ->128) + max; block(256) per center, split-K over s ----
__launch_bounds__(256)
__global__ void k_sa2mlp(const float* __restrict__ f1, const int* __restrict__ nidx2,
                         const float* __restrict__ w1, const float* __restrict__ b1,
                         const float* __restrict__ w2, const float* __restrict__ b2,
                         float* __restrict__ f2) {
  __shared__ __align__(16) float fin[64];
  __shared__ __align__(16) float h1s[128];
  __shared__ float ph[128];
  const int tid = threadIdx.x;
  const int s = tid >> 7, t = tid & 127;
  const int q = blockIdx.x;
  const int b = q >> 7;
  float w1r[32], w2r[64];
  #pragma unroll
  for (int i = 0; i < 32; ++i) w1r[i] = w1[(s*32 + i)*128 + t];
  #pragma unroll
  for (int h = 0; h < 64; ++h) w2r[h] = w2[(s*64 + h)*128 + t];
  float b1v = b1[t], b2v = b2[t];
  const int* nb = nidx2 + (size_t)q * 32;
  float fm = -3.402823466e+38f;
  for (int j = 0; j < 32; ++j) {
    int n = nb[j];
    __syncthreads();
    if (tid < 64) fin[tid] = f1[((size_t)b * S1_ + n)*64 + tid];
    __syncthreads();
    float p1 = 0.0f;
    const float4* fv = (const float4*)(fin + s*32);
    #pragma unroll
    for (int i4 = 0; i4 < 8; ++i4) {
      float4 v = fv[i4];
      p1 = fmaf(v.x, w1r[4*i4+0], p1);
      p1 = fmaf(v.y, w1r[4*i4+1], p1);
      p1 = fmaf(v.z, w1r[4*i4+2], p1);
      p1 = fmaf(v.w, w1r[4*i4+3], p1);
    }
    if (s) ph[t] = p1;
    __syncthreads();
    if (!s) h1s[t] = fmaxf(p1 + ph[t] + b1v, 0.0f);
    __syncthreads();
    float p2 = 0.0f;
    const float4* hv = (const float4*)(h1s + s*64);
    #pragma unroll
    for (int h4 = 0; h4 < 16; ++h4) {
      float4 v = hv[h4];
      p2 = fmaf(v.x, w2r[4*h4+0], p2);
      p2 = fmaf(v.y, w2r[4*h4+1], p2);
      p2 = fmaf(v.z, w2r[4*h4+2], p2);
      p2 = fmaf(v.w, w2r[4*h4+3], p2);
    }
    if (s) ph[t] = p2;
    __syncthreads();
    if (!s) fm = fmaxf(fm, p2 + ph[t] + b2v);
  }
  if (!s) f2[(size_t)q*128 + t] = fm;
}

// ---- FP1: kNN-3 over 128 refs + interp + MLP(192->64 relu ->64); wave per query ----
__launch_bounds__(256)
__global__ void k_fp1(const float* __restrict__ c1, const float* __restrict__ c2,
                      const float* __restrict__ f1, const float* __restrict__ f2,
                      const float* __restrict__ w1, const float* __restrict__ b1,
                      const float* __restrict__ w2, const float* __restrict__ b2,
                      float* __restrict__ g1) {
  __shared__ __align__(16) float sw1[192*64];
  __shared__ __align__(16) float sw2[64*64];
  __shared__ __align__(16) float sinp[4][192];
  __shared__ __align__(16) float sh1[4][64];
  __shared__ __align__(16) float4 srefs4[S2_];
  const int tid = threadIdx.x;
  const int wave = tid >> 6, lane = tid & 63;
  const int q = blockIdx.x * 4 + wave;
  const int b = q >> 9;
  for (int i = tid; i < 192*64; i += 256) sw1[i] = w1[i];
  for (int i = tid; i < 64*64; i += 256) sw2[i] = w2[i];
  if (tid < S2_) {
    const float* rp = c2 + ((size_t)b * S2_ + tid) * 3;
    float rx = rp[0], ry = rp[1], rz = rp[2];
    srefs4[tid] = make_float4(rx, ry, rz, rx*rx + ry*ry + rz*rz);
  }
  __syncthreads();
  float qx = c1[(size_t)q*3+0], qy = c1[(size_t)q*3+1], qz = c1[(size_t)q*3+2];
  float qq = qx*qx + qy*qy + qz*qz;
  unsigned long long ka, kb;
  {
    float4 rv = srefs4[lane];
    float dot = qx*rv.x + qy*rv.y + qz*rv.z;
    float d = (qq - 2.0f*dot) + rv.w;
    unsigned int ub = __float_as_uint(d);
    ub ^= ((unsigned int)((int)ub >> 31)) | 0x80000000u;
    ka = ((unsigned long long)ub << 32) | (unsigned int)lane;
    rv = srefs4[lane + 64];
    dot = qx*rv.x + qy*rv.y + qz*rv.z;
    d = (qq - 2.0f*dot) + rv.w;
    ub = __float_as_uint(d);
    ub ^= ((unsigned int)((int)ub >> 31)) | 0x80000000u;
    kb = ((unsigned long long)ub << 32) | (unsigned int)(lane + 64);
    if (kb < ka) { unsigned long long tt = ka; ka = kb; kb = tt; }
  }
  int nsel[3];
  #pragma unroll
  for (int r = 0; r < 3; ++r) {
    unsigned long long m = ka;
    #pragma unroll
    for (int s = 1; s < 64; s <<= 1) {
      unsigned long long o = __shfl_xor(m, s);
      if (o < m) m = o;
    }
    nsel[r] = (int)(m & 0xffffffffu);
    if (ka == m) { ka = kb; kb = ~0ULL; }
  }
  const float* f2b = f2 + (size_t)b * S2_ * 128;
  sinp[wave][lane] = f1[(size_t)q*64 + lane];
  {
    float a0 = f2b[(size_t)nsel[0]*128 + lane];
    float a1 = f2b[(size_t)nsel[1]*128 + lane];
    float a2 = f2b[(size_t)nsel[2]*128 + lane];
    sinp[wave][64 + lane] = (a0 + a1 + a2) / 3.0f;
    a0 = f2b[(size_t)nsel[0]*128 + 64 + lane];
    a1 = f2b[(size_t)nsel[1]*128 + 64 + lane];
    a2 = f2b[(size_t)nsel[2]*128 + 64 + lane];
    sinp[wave][128 + lane] = (a0 + a1 + a2) / 3.0f;
  }
  __syncthreads();
  float acc = b1[lane];
  const float4* sv = (const float4*)(&sinp[wave][0]);
  #pragma unroll
  for (int i4 = 0; i4 < 48; ++i4) {
    float4 v = sv[i4];
    acc = fmaf(v.x, sw1[(4*i4+0)*64 + lane], acc);
    acc = fmaf(v.y, sw1[(4*i4+1)*64 + lane], acc);
    acc = fmaf(v.z, sw1[(4*i4+2)*64 + lane], acc);
    acc = fmaf(v.w, sw1[(4*i4+3)*64 + lane], acc);
  }
  sh1[wave][lane] = fmaxf(acc, 0.0f);
  __syncthreads();
  float acc2 = b2[lane];
  const float4* hv = (const float4*)(&sh1[wave][0]);
  #pragma unroll
  for (int h4 = 0; h4 < 16; ++h4) {
    float4 v = hv[h4];
    acc2 = fmaf(v.x, sw2[(4*h4+0)*64 + lane], acc2);
    acc2 = fmaf(v.y, sw2[(4*h4+1)*64 + lane], acc2);
    acc2 = fmaf(v.z, sw2[(4*h4+2)*64 + lane], acc2);
    acc2 = fmaf(v.w, sw2[(4*h4+3)*64 + lane], acc2);
  }
  g1[(size_t)q*64 + lane] = acc2;
}

// ---- FP2: kNN-3 over 512 refs + interp + MLP(67->32 relu ->32) + FC + log_softmax ----
__launch_bounds__(256)
__global__ void k_fp2(const float* __restrict__ x, const float* __restrict__ c1,
                      const float* __restrict__ g1,
                      const float* __restrict__ w1, const float* __restrict__ b1,
                      const float* __restrict__ w2, const float* __restrict__ b2,
                      const float* __restrict__ fcw, const float* __restrict__ fcb,
                      float* __restrict__ out) {
  __shared__ __align__(16) float4 srefs4[S1_];
  __shared__ __align__(16) float sw1[67*32];
  __shared__ __align__(16) float sw2[32*32];
  __shared__ __align__(16) float sfc[64];
  __shared__ float sb1[32], sb2[32], sfcb[2];
  const int tid = threadIdx.x;
  const int b = blockIdx.x >> 7;
  const int n = ((blockIdx.x & 127) << 8) + tid;
  const float* c1b = c1 + (size_t)b * S1_ * 3;
  for (int i = tid; i < S1_; i += 256) {
    float rx = c1b[3*i], ry = c1b[3*i+1], rz = c1b[3*i+2];
    srefs4[i] = make_float4(rx, ry, rz, rx*rx + ry*ry + rz*rz);
  }
  for (int i = tid; i < 67*32; i += 256) sw1[i] = w1[i];
  for (int i = tid; i < 32*32; i += 256) sw2[i] = w2[i];
  if (tid < 64) sfc[tid] = fcw[tid];
  if (tid < 32) { sb1[tid] = b1[tid]; sb2[tid] = b2[tid]; }
  if (tid < 2) sfcb[tid] = fcb[tid];
  __syncthreads();
  const float* xb = x + (size_t)b * N_ * 3;
  float qx = xb[3*n], qy = xb[3*n+1], qz = xb[3*n+2];
  float qq = qx*qx + qy*qy + qz*qz;
  unsigned long long k0 = ~0ULL, k1 = ~0ULL, k2 = ~0ULL;
  for (int r = 0; r < S1_; ++r) {
    float4 rv = srefs4[r];
    float dot = qx*rv.x + qy*rv.y + qz*rv.z;
    float d = (qq - 2.0f*dot) + rv.w;
    unsigned int ub = __float_as_uint(d);
    ub ^= ((unsigned int)((int)ub >> 31)) | 0x80000000u;
    unsigned long long kk = ((unsigned long long)ub << 32) | (unsigned int)r;
    if (kk < k2) {
      if (kk < k1) { k2 = k1; if (kk < k0) { k1 = k0; k0 = kk; } else k1 = kk; }
      else k2 = kk;
    }
  }
  int i0 = (int)(k0 & 0xffffffffu), i1 = (int)(k1 & 0xffffffffu), i2 = (int)(k2 & 0xffffffffu);
  const float* g1b = g1 + (size_t)b * S1_ * 64;
  const float4* p0 = (const float4*)(g1b + (size_t)i0 * 64);
  const float4* p1 = (const float4*)(g1b + (size_t)i1 * 64);
  const float4* p2 = (const float4*)(g1b + (size_t)i2 * 64);
  float fi[64];
  #pragma unroll
  for (int o = 0; o < 16; ++o) {
    float4 a = p0[o], bb = p1[o], cc = p2[o];
    fi[4*o+0] = (a.x + bb.x + cc.x) / 3.0f;
    fi[4*o+1] = (a.y + bb.y + cc.y) / 3.0f;
    fi[4*o+2] = (a.z + bb.z + cc.z) / 3.0f;
    fi[4*o+3] = (a.w + bb.w + cc.w) / 3.0f;
  }
  float h1r[32];
  #pragma unroll
  for (int k = 0; k < 32; ++k) h1r[k] = sb1[k];
  #pragma unroll
  for (int i = 0; i < 67; ++i) {
    float v = (i == 0) ? qx : (i == 1) ? qy : (i == 2) ? qz : fi[i-3];
    const float4* wrow = (const float4*)(sw1 + i*32);
    #pragma unroll
    for (int kq = 0; kq < 8; ++kq) {
      float4 wv = wrow[kq];
      h1r[4*kq+0] = fmaf(v, wv.x, h1r[4*kq+0]);
      h1r[4*kq+1] = fmaf(v, wv.y, h1r[4*kq+1]);
      h1r[4*kq+2] = fmaf(v, wv.z, h1r[4*kq+2]);
      h1r[4*kq+3] = fmaf(v, wv.w, h1r[4*kq+3]);
    }
  }
  #pragma unroll
  for (int k = 0; k < 32; ++k) h1r[k] = fmaxf(h1r[k], 0.0f);
  float h2r[32];
  #pragma unroll
  for (int m = 0; m < 32; ++m) h2r[m] = sb2[m];
  #pragma unroll
  for (int k = 0; k < 32; ++k) {
    float v = h1r[k];
    const float4* wrow = (const float4*)(sw2 + k*32);
    #pragma unroll
    for (int mq = 0; mq < 8; ++mq) {
      float4 wv = wrow[mq];
      h2r[4*mq+0] = fmaf(v, wv.x, h2r[4*mq+0]);
      h2r[4*mq+1] = fmaf(v, wv.y, h2r[4*mq+1]);
      h2r[4*mq+2] = fmaf(v, wv.z, h2r[4*mq+2]);
      h2r[4*mq+3] = fmaf(v, wv.w, h2r[4*mq+3]);
    }
  }
  float l0 = sfcb[0], l1 = sfcb[1];
  #pragma unroll
  for (int m = 0; m < 32; ++m) {
    l0 = fmaf(h2r[m], sfc[2*m+0], l0);
    l1 = fmaf(h2r[m], sfc[2*m+1], l1);
  }
  float mx = fmaxf(l0, l1);
  float s0 = l0 - mx, s1 = l1 - mx;
  float lg = logf(expf(s0) + expf(s1));
  float2 res; res.x = s0 - lg; res.y = s1 - lg;
  ((float2*)out)[(size_t)b * N_ + n] = res;
}

// ================= launch =================
extern "C" void kernel_launch(void* const* d_in, const int* in_sizes, int n_in,
                              void* d_out, int out_size, void* d_ws, size_t ws_size,
                              hipStream_t stream) {
  (void)in_sizes; (void)n_in; (void)out_size; (void)ws_size;
  const float* x     = (const float*)d_in[0];
  const float* sa1w1 = (const float*)d_in[1];
  const float* sa1b1 = (const float*)d_in[2];
  const float* sa1w2 = (const float*)d_in[3];
  const float* sa1b2 = (const float*)d_in[4];
  const float* sa2w1 = (const float*)d_in[5];
  const float* sa2b1 = (const float*)d_in[6];
  const float* sa2w2 = (const float*)d_in[7];
  const float* sa2b2 = (const float*)d_in[8];
  const float* fp1w1 = (const float*)d_in[9];
  const float* fp1b1 = (const float*)d_in[10];
  const float* fp1w2 = (const float*)d_in[11];
  const float* fp1b2 = (const float*)d_in[12];
  const float* fp2w1 = (const float*)d_in[13];
  const float* fp2b1 = (const float*)d_in[14];
  const float* fp2w2 = (const float*)d_in[15];
  const float* fp2b2 = (const float*)d_in[16];
  const float* fcw   = (const float*)d_in[17];
  const float* fcb   = (const float*)d_in[18];
  float* out = (float*)d_out;
  char* ws = (char*)d_ws;
  float4* xr4  = (float4*)(ws + OFF_XR4);
  float*  c1   = (float*)(ws + OFF_C1);
  float4* c1r4 = (float4*)(ws + OFF_C1R4);
  float*  c2   = (float*)(ws + OFF_C2);
  int*    nidx1= (int*)(ws + OFF_NIDX1);
  float*  f1   = (float*)(ws + OFF_F1);
  int*    nidx2= (int*)(ws + OFF_NIDX2);
  float*  f2   = (float*)(ws + OFF_F2);
  float*  g1   = (float*)(ws + OFF_G1);

  Samps smp;
  compute_samples(smp.s1, smp.s2);

  hipLaunchKernelGGL(k_prep,    dim3(B_*N_/256), dim3(256), 0, stream, x, xr4);
  hipLaunchKernelGGL(k_centers, dim3((B_*(S1_+S2_)+255)/256), dim3(256), 0, stream,
                     x, smp, c1, c1r4, c2);
  hipLaunchKernelGGL(k_knn,     dim3(B_*S1_/4), dim3(256), 0, stream, xr4, c1, nidx1, N_, 9);
  hipLaunchKernelGGL(k_sa1mlp,  dim3(B_*S1_/4), dim3(256), 0, stream,
                     x, nidx1, sa1w1, sa1b1, sa1w2, sa1b2, f1);
  hipLaunchKernelGGL(k_knn,     dim3(B_*S2_/4), dim3(256), 0, stream, c1r4, c2, nidx2, S1_, 7);
  hipLaunchKernelGGL(k_sa2mlp,  dim3(B_*S2_), dim3(256), 0, stream,
                     f1, nidx2, sa2w1, sa2b1, sa2w2, sa2b2, f2);
  hipLaunchKernelGGL(k_fp1,     dim3(B_*S1_/4), dim3(256), 0, stream,
                     c1, c2, f1, f2, fp1w1, fp1b1, fp1w2, fp1b2, g1);
  hipLaunchKernelGGL(k_fp2,     dim3(B_*N_/256), dim3(256), 0, stream,
                     x, c1, g1, fp2w1, fp2b1, fp2w2, fp2b2, fcw, fcb, out);
}

// Round 6
// 465.344 us; speedup vs baseline: 1.2397x; 1.2397x over previous
//
#include <hip/hip_runtime.h>
#include <stdint.h>

#define B_ 8
#define N_ 32768
#define S1_ 512
#define S2_ 128

// ---------------- workspace layout (bytes) ----------------
#define OFF_XR4   ((size_t)0)        // B*N float4 (xyz, rr)          4194304
#define OFF_C1    ((size_t)4194304)  // B*512*3 f32                     49152
#define OFF_C1R4  ((size_t)4243456)  // B*512 float4                    65536
#define OFF_C2    ((size_t)4308992)  // B*128*3 f32                     12288
#define OFF_NIDX1 ((size_t)4321280)  // B*512*32 i32                   524288
#define OFF_F1    ((size_t)4845568)  // B*512*64 f32                   524288
#define OFF_NIDX2 ((size_t)5369856)  // B*128*32 i32                   131072
#define OFF_F2    ((size_t)5500928)  // B*128*128 f32                  524288
#define OFF_G1    ((size_t)6025216)  // B*512*64 f32                   524288

struct Samps { int s1[S1_]; int s2[S2_]; };

// ================= host: replicate np.random.default_rng(0) =================
typedef unsigned __int128 u128;
struct RngState { u128 state, inc; bool has32; uint32_t saved; };

static uint64_t rng_next64(RngState* r) {
  const u128 MULT = ((u128)0x2360ed051fc65da4ULL << 64) | 0x4385df649fccf645ULL;
  r->state = r->state * MULT + r->inc;
  uint64_t hi = (uint64_t)(r->state >> 64), lo = (uint64_t)r->state;
  uint64_t xs = hi ^ lo;
  unsigned rot = (unsigned)(r->state >> 122);
  return (xs >> rot) | (xs << ((64u - rot) & 63u));
}
static uint32_t rng_next32(RngState* r) {
  if (r->has32) { r->has32 = false; return r->saved; }
  uint64_t v = rng_next64(r);
  r->has32 = true; r->saved = (uint32_t)(v >> 32);
  return (uint32_t)v;
}
static uint32_t rng_interval(RngState* r, uint32_t mx) {
  if (mx == 0) return 0;
  uint32_t mask = mx;
  mask |= mask >> 1; mask |= mask >> 2; mask |= mask >> 4;
  mask |= mask >> 8; mask |= mask >> 16;
  uint32_t v;
  while ((v = (rng_next32(r) & mask)) > mx) {}
  return v;
}
static void compute_samples(int* s1, int* s2) {
  uint32_t pool[4];
  uint32_t hc = 0x43b0d7e5u;
  auto hmix = [&hc](uint32_t v) -> uint32_t {
    v ^= hc; hc *= 0x931e8875u; v *= hc; v ^= v >> 16; return v;
  };
  auto mixf = [](uint32_t x, uint32_t y) -> uint32_t {
    uint32_t rr = (x * 0xca01f9ddu) ^ (y * 0x4973f715u);
    rr ^= rr >> 16; return rr;
  };
  pool[0] = hmix(0u); pool[1] = hmix(0u); pool[2] = hmix(0u); pool[3] = hmix(0u);
  for (int s = 0; s < 4; ++s)
    for (int d = 0; d < 4; ++d)
      if (s != d) pool[d] = mixf(pool[d], hmix(pool[s]));
  uint32_t hc2 = 0x8b51f9ddu;
  uint32_t w32[8];
  for (int i = 0; i < 8; ++i) {
    uint32_t dv = pool[i & 3];
    dv ^= hc2; hc2 *= 0x58f38dedu; dv *= hc2; dv ^= dv >> 16;
    w32[i] = dv;
  }
  uint64_t w64[4];
  for (int i = 0; i < 4; ++i) w64[i] = (uint64_t)w32[2*i] | ((uint64_t)w32[2*i+1] << 32);
  const u128 MULT = ((u128)0x2360ed051fc65da4ULL << 64) | 0x4385df649fccf645ULL;
  u128 initstate = ((u128)w64[0] << 64) | w64[1];
  u128 initseq   = ((u128)w64[2] << 64) | w64[3];
  RngState r; r.has32 = false; r.saved = 0;
  r.inc = (initseq << 1) | 1;
  r.state = 0;
  r.state = r.state * MULT + r.inc;
  r.state += initstate;
  r.state = r.state * MULT + r.inc;
  static int perm1[N_];
  for (int i = 0; i < N_; ++i) perm1[i] = i;
  for (int i = N_ - 1; i > 0; --i) {
    uint32_t j = rng_interval(&r, (uint32_t)i);
    int t = perm1[i]; perm1[i] = perm1[j]; perm1[j] = t;
  }
  for (int i = 0; i < S1_; ++i) s1[i] = perm1[i];
  int perm2[S1_];
  for (int i = 0; i < S1_; ++i) perm2[i] = i;
  for (int i = S1_ - 1; i > 0; --i) {
    uint32_t j = rng_interval(&r, (uint32_t)i);
    int t = perm2[i]; perm2[i] = perm2[j]; perm2[j] = t;
  }
  for (int i = 0; i < S2_; ++i) s2[i] = perm2[i];
}

// ================= device =================

__global__ void k_prep(const float* __restrict__ x, float4* __restrict__ xr4) {
  int t = blockIdx.x * blockDim.x + threadIdx.x;
  float a = x[3*t], b = x[3*t+1], c = x[3*t+2];
  xr4[t] = make_float4(a, b, c, a*a + b*b + c*c);
}

__global__ void k_centers(const float* __restrict__ x, Samps sm,
                          float* __restrict__ c1, float4* __restrict__ c1r4,
                          float* __restrict__ c2) {
  int t = blockIdx.x * blockDim.x + threadIdx.x;
  if (t < B_*S1_) {
    int b = t >> 9, c = t & (S1_-1);
    int sidx = sm.s1[c];
    const float* src = x + ((size_t)b*N_ + sidx)*3;
    float a = src[0], bb = src[1], cc = src[2];
    c1[(size_t)t*3+0] = a; c1[(size_t)t*3+1] = bb; c1[(size_t)t*3+2] = cc;
    c1r4[t] = make_float4(a, bb, cc, a*a + bb*bb + cc*cc);
  } else {
    int u = t - B_*S1_;
    if (u < B_*S2_) {
      int b = u >> 7, c = u & (S2_-1);
      int sidx = sm.s1[sm.s2[c]];
      const float* src = x + ((size_t)b*N_ + sidx)*3;
      c2[(size_t)u*3+0] = src[0]; c2[(size_t)u*3+1] = src[1]; c2[(size_t)u*3+2] = src[2];
    }
  }
}

// ---- kNN: one wave per query; sorted top-32 list (lane i = i-th best),
//      serial sorted-insert (expected ~250 inserts/query), bitonic prologue ----
#define KNN_KEY(RV, UB)                                                     \
  {                                                                         \
    float dot = qx*(RV).x + qy*(RV).y + qz*(RV).z;                          \
    float dd = (qq - 2.0f*dot) + (RV).w;                                    \
    (UB) = __float_as_uint(dd);                                             \
    (UB) ^= ((unsigned int)((int)(UB) >> 31)) | 0x80000000u;                \
  }

#define KNN_INSERT(UB, PBASE)                                               \
  {                                                                         \
    bool cand = ((UB) < T);                                                 \
    while (__any(cand)) {                                                   \
      unsigned long long bal = __ballot(cand);                              \
      int src = (int)__builtin_ctzll(bal);                                  \
      unsigned int ikd = (unsigned int)__shfl((int)(UB), src);              \
      unsigned int iki = (unsigned int)((PBASE) + src);                     \
      int pos = __popcll(__ballot(ld <= ikd));                              \
      unsigned int ud = (unsigned int)__shfl_up((int)ld, 1);                \
      unsigned int ui = (unsigned int)__shfl_up((int)li, 1);                \
      if (lane == pos)      { ld = ikd; li = iki; }                         \
      else if (lane > pos)  { ld = ud;  li = ui;  }                         \
      T = (unsigned int)__shfl((int)ld, 31);                                \
      cand = cand && ((UB) < T) && (lane != src);                           \
    }                                                                       \
  }

__launch_bounds__(256)
__global__ void k_knn(const float4* __restrict__ refs4, const float* __restrict__ qpts,
                      int* __restrict__ out_idx, int nrefs, int qshift) {
  const int tid = threadIdx.x, lane = tid & 63;
  const int q = blockIdx.x * 4 + (tid >> 6);
  const int b = q >> qshift;
  const float4* refs = refs4 + (size_t)b * nrefs;
  float qx = qpts[(size_t)q*3+0], qy = qpts[(size_t)q*3+1], qz = qpts[(size_t)q*3+2];
  float qq = qx*qx + qy*qy + qz*qz;
  unsigned int ld, li, T;
  {
    // prologue: first 64 refs via one bitonic sort (avoids 64 serial inserts at T=inf)
    float4 rv = refs[lane];
    unsigned int ub; KNN_KEY(rv, ub);
    unsigned long long key = ((unsigned long long)ub << 32) | (unsigned int)lane;
    #pragma unroll
    for (int k2 = 2; k2 <= 64; k2 <<= 1) {
      #pragma unroll
      for (int j = k2 >> 1; j >= 1; j >>= 1) {
        unsigned long long o = __shfl_xor(key, j);
        bool keepmin = (((lane & j) == 0) == ((lane & k2) == 0));
        if ((o < key) == keepmin) key = o;
      }
    }
    ld = (unsigned int)(key >> 32);
    li = (unsigned int)key;
    T = (unsigned int)__shfl((int)ld, 31);
  }
  {
    // rest of group 0 (refs 64..255)
    float4 r1 = refs[64 + lane];
    float4 r2 = refs[128 + lane];
    float4 r3 = refs[192 + lane];
    unsigned int u1, u2, u3;
    KNN_KEY(r1, u1); KNN_KEY(r2, u2); KNN_KEY(r3, u3);
    KNN_INSERT(u1, 64);
    KNN_INSERT(u2, 128);
    KNN_INSERT(u3, 192);
  }
  for (int g = 256; g + 255 < nrefs; g += 256) {
    float4 r0 = refs[g + lane];
    float4 r1 = refs[g + 64 + lane];
    float4 r2 = refs[g + 128 + lane];
    float4 r3 = refs[g + 192 + lane];
    unsigned int u0, u1, u2, u3;
    KNN_KEY(r0, u0); KNN_KEY(r1, u1); KNN_KEY(r2, u2); KNN_KEY(r3, u3);
    KNN_INSERT(u0, g);
    KNN_INSERT(u1, g + 64);
    KNN_INSERT(u2, g + 128);
    KNN_INSERT(u3, g + 192);
  }
  if (lane < 32) out_idx[(size_t)q*32 + lane] = (int)li;
}

// ---- SA1 MLP (3->64 relu ->64) + max over 32 neighbors; wave per center.
//      Wave-private LDS broadcast => NO barriers; pipelined neighbor gather. ----
__launch_bounds__(256)
__global__ void k_sa1mlp(const float* __restrict__ x, const int* __restrict__ nidx1,
                         const float* __restrict__ w1, const float* __restrict__ b1,
                         const float* __restrict__ w2, const float* __restrict__ b2,
                         float* __restrict__ f1) {
  __shared__ __align__(16) float hbuf[4][64];
  const int tid = threadIdx.x, wave = tid >> 6, lane = tid & 63;
  const int q = blockIdx.x * 4 + wave;
  const int b = q >> 9;
  const float* xb = x + (size_t)b * N_ * 3;
  float wc0 = w1[lane], wc1 = w1[64 + lane], wc2 = w1[128 + lane];
  float b1v = b1[lane], b2v = b2[lane];
  float w2c[64];
  #pragma unroll
  for (int h = 0; h < 64; ++h) w2c[h] = w2[h*64 + lane];
  const int* nb = nidx1 + (size_t)q * 32;
  int n0 = nb[0];
  float px = xb[3*n0], py = xb[3*n0+1], pz = xb[3*n0+2];
  float fm = -3.402823466e+38f;
  for (int j = 0; j < 32; ++j) {
    int n2 = nb[(j + 1) & 31];
    float nx = xb[3*n2], ny = xb[3*n2+1], nz = xb[3*n2+2];
    float h1 = fmaf(px, wc0, fmaf(py, wc1, fmaf(pz, wc2, b1v)));
    h1 = fmaxf(h1, 0.0f);
    hbuf[wave][lane] = h1;                    // wave-private: no barrier needed
    float acc = b2v;
    const float4* hv = (const float4*)(&hbuf[wave][0]);
    #pragma unroll
    for (int h4 = 0; h4 < 16; ++h4) {
      float4 v = hv[h4];
      acc = fmaf(v.x, w2c[4*h4+0], acc);
      acc = fmaf(v.y, w2c[4*h4+1], acc);
      acc = fmaf(v.z, w2c[4*h4+2], acc);
      acc = fmaf(v.w, w2c[4*h4+3], acc);
    }
    fm = fmaxf(fm, acc);
    px = nx; py = ny; pz = nz;
  }
  f1[(size_t)q*64 + lane] = fm;
}

// ---- SA2 MLP (64->128 relu ->128) + max; block(256) per center, split-K over s ----
__launch_bounds__(256)
__global__ void k_sa2mlp(const float* __restrict__ f1, const int* __restrict__ nidx2,
                         const float* __restrict__ w1, const float* __restrict__ b1,
                         const float* __restrict__ w2, const float* __restrict__ b2,
                         float* __restrict__ f2) {
  __shared__ __align__(16) float fin[64];
  __shared__ __align__(16) float h1s[128];
  __shared__ float ph[128];
  const int tid = threadIdx.x;
  const int s = tid >> 7, t = tid & 127;
  const int q = blockIdx.x;
  const int b = q >> 7;
  float w1r[32], w2r[64];
  #pragma unroll
  for (int i = 0; i < 32; ++i) w1r[i] = w1[(s*32 + i)*128 + t];
  #pragma unroll
  for (int h = 0; h < 64; ++h) w2r[h] = w2[(s*64 + h)*128 + t];
  float b1v = b1[t], b2v = b2[t];
  const int* nb = nidx2 + (size_t)q * 32;
  float fm = -3.402823466e+38f;
  for (int j = 0; j < 32; ++j) {
    int n = nb[j];
    __syncthreads();
    if (tid < 64) fin[tid] = f1[((size_t)b * S1_ + n)*64 + tid];
    __syncthreads();
    float p1 = 0.0f;
    const float4* fv = (const float4*)(fin + s*32);
    #pragma unroll
    for (int i4 = 0; i4 < 8; ++i4) {
      float4 v = fv[i4];
      p1 = fmaf(v.x, w1r[4*i4+0], p1);
      p1 = fmaf(v.y, w1r[4*i4+1], p1);
      p1 = fmaf(v.z, w1r[4*i4+2], p1);
      p1 = fmaf(v.w, w1r[4*i4+3], p1);
    }
    if (s) ph[t] = p1;
    __syncthreads();
    if (!s) h1s[t] = fmaxf(p1 + ph[t] + b1v, 0.0f);
    __syncthreads();
    float p2 = 0.0f;
    const float4* hv = (const float4*)(h1s + s*64);
    #pragma unroll
    for (int h4 = 0; h4 < 16; ++h4) {
      float4 v = hv[h4];
      p2 = fmaf(v.x, w2r[4*h4+0], p2);
      p2 = fmaf(v.y, w2r[4*h4+1], p2);
      p2 = fmaf(v.z, w2r[4*h4+2], p2);
      p2 = fmaf(v.w, w2r[4*h4+3], p2);
    }
    if (s) ph[t] = p2;
    __syncthreads();
    if (!s) fm = fmaxf(fm, p2 + ph[t] + b2v);
  }
  if (!s) f2[(size_t)q*128 + t] = fm;
}

// ---- FP1: kNN-3 over 128 refs + interp + MLP(192->64 relu ->64); wave per query ----
__launch_bounds__(256)
__global__ void k_fp1(const float* __restrict__ c1, const float* __restrict__ c2,
                      const float* __restrict__ f1, const float* __restrict__ f2,
                      const float* __restrict__ w1, const float* __restrict__ b1,
                      const float* __restrict__ w2, const float* __restrict__ b2,
                      float* __restrict__ g1) {
  __shared__ __align__(16) float sw1[192*64];
  __shared__ __align__(16) float sw2[64*64];
  __shared__ __align__(16) float sinp[4][192];
  __shared__ __align__(16) float sh1[4][64];
  __shared__ __align__(16) float4 srefs4[S2_];
  const int tid = threadIdx.x;
  const int wave = tid >> 6, lane = tid & 63;
  const int q = blockIdx.x * 4 + wave;
  const int b = q >> 9;
  for (int i = tid; i < 192*64; i += 256) sw1[i] = w1[i];
  for (int i = tid; i < 64*64; i += 256) sw2[i] = w2[i];
  if (tid < S2_) {
    const float* rp = c2 + ((size_t)b * S2_ + tid) * 3;
    float rx = rp[0], ry = rp[1], rz = rp[2];
    srefs4[tid] = make_float4(rx, ry, rz, rx*rx + ry*ry + rz*rz);
  }
  __syncthreads();
  float qx = c1[(size_t)q*3+0], qy = c1[(size_t)q*3+1], qz = c1[(size_t)q*3+2];
  float qq = qx*qx + qy*qy + qz*qz;
  unsigned long long ka, kb;
  {
    float4 rv = srefs4[lane];
    float dot = qx*rv.x + qy*rv.y + qz*rv.z;
    float d = (qq - 2.0f*dot) + rv.w;
    unsigned int ub = __float_as_uint(d);
    ub ^= ((unsigned int)((int)ub >> 31)) | 0x80000000u;
    ka = ((unsigned long long)ub << 32) | (unsigned int)lane;
    rv = srefs4[lane + 64];
    dot = qx*rv.x + qy*rv.y + qz*rv.z;
    d = (qq - 2.0f*dot) + rv.w;
    ub = __float_as_uint(d);
    ub ^= ((unsigned int)((int)ub >> 31)) | 0x80000000u;
    kb = ((unsigned long long)ub << 32) | (unsigned int)(lane + 64);
    if (kb < ka) { unsigned long long tt = ka; ka = kb; kb = tt; }
  }
  int nsel[3];
  #pragma unroll
  for (int r = 0; r < 3; ++r) {
    unsigned long long m = ka;
    #pragma unroll
    for (int s = 1; s < 64; s <<= 1) {
      unsigned long long o = __shfl_xor(m, s);
      if (o < m) m = o;
    }
    nsel[r] = (int)(m & 0xffffffffu);
    if (ka == m) { ka = kb; kb = ~0ULL; }
  }
  const float* f2b = f2 + (size_t)b * S2_ * 128;
  sinp[wave][lane] = f1[(size_t)q*64 + lane];
  {
    float a0 = f2b[(size_t)nsel[0]*128 + lane];
    float a1 = f2b[(size_t)nsel[1]*128 + lane];
    float a2 = f2b[(size_t)nsel[2]*128 + lane];
    sinp[wave][64 + lane] = (a0 + a1 + a2) / 3.0f;
    a0 = f2b[(size_t)nsel[0]*128 + 64 + lane];
    a1 = f2b[(size_t)nsel[1]*128 + 64 + lane];
    a2 = f2b[(size_t)nsel[2]*128 + 64 + lane];
    sinp[wave][128 + lane] = (a0 + a1 + a2) / 3.0f;
  }
  __syncthreads();
  float acc = b1[lane];
  const float4* sv = (const float4*)(&sinp[wave][0]);
  #pragma unroll
  for (int i4 = 0; i4 < 48; ++i4) {
    float4 v = sv[i4];
    acc = fmaf(v.x, sw1[(4*i4+0)*64 + lane], acc);
    acc = fmaf(v.y, sw1[(4*i4+1)*64 + lane], acc);
    acc = fmaf(v.z, sw1[(4*i4+2)*64 + lane], acc);
    acc = fmaf(v.w, sw1[(4*i4+3)*64 + lane], acc);
  }
  sh1[wave][lane] = fmaxf(acc, 0.0f);
  __syncthreads();
  float acc2 = b2[lane];
  const float4* hv = (const float4*)(&sh1[wave][0]);
  #pragma unroll
  for (int h4 = 0; h4 < 16; ++h4) {
    float4 v = hv[h4];
    acc2 = fmaf(v.x, sw2[(4*h4+0)*64 + lane], acc2);
    acc2 = fmaf(v.y, sw2[(4*h4+1)*64 + lane], acc2);
    acc2 = fmaf(v.z, sw2[(4*h4+2)*64 + lane], acc2);
    acc2 = fmaf(v.w, sw2[(4*h4+3)*64 + lane], acc2);
  }
  g1[(size_t)q*64 + lane] = acc2;
}

// ---- FP2: kNN-3 over 512 refs + interp + MLP(67->32 relu ->32) + FC + log_softmax ----
__launch_bounds__(256)
__global__ void k_fp2(const float* __restrict__ x, const float* __restrict__ c1,
                      const float* __restrict__ g1,
                      const float* __restrict__ w1, const float* __restrict__ b1,
                      const float* __restrict__ w2, const float* __restrict__ b2,
                      const float* __restrict__ fcw, const float* __restrict__ fcb,
                      float* __restrict__ out) {
  __shared__ __align__(16) float4 srefs4[S1_];
  __shared__ __align__(16) float sw1[67*32];
  __shared__ __align__(16) float sw2[32*32];
  __shared__ __align__(16) float sfc[64];
  __shared__ float sb1[32], sb2[32], sfcb[2];
  const int tid = threadIdx.x;
  const int b = blockIdx.x >> 7;
  const int n = ((blockIdx.x & 127) << 8) + tid;
  const float* c1b = c1 + (size_t)b * S1_ * 3;
  for (int i = tid; i < S1_; i += 256) {
    float rx = c1b[3*i], ry = c1b[3*i+1], rz = c1b[3*i+2];
    srefs4[i] = make_float4(rx, ry, rz, rx*rx + ry*ry + rz*rz);
  }
  for (int i = tid; i < 67*32; i += 256) sw1[i] = w1[i];
  for (int i = tid; i < 32*32; i += 256) sw2[i] = w2[i];
  if (tid < 64) sfc[tid] = fcw[tid];
  if (tid < 32) { sb1[tid] = b1[tid]; sb2[tid] = b2[tid]; }
  if (tid < 2) sfcb[tid] = fcb[tid];
  __syncthreads();
  const float* xb = x + (size_t)b * N_ * 3;
  float qx = xb[3*n], qy = xb[3*n+1], qz = xb[3*n+2];
  float qq = qx*qx + qy*qy + qz*qz;
  unsigned long long k0 = ~0ULL, k1 = ~0ULL, k2 = ~0ULL;
  for (int r = 0; r < S1_; ++r) {
    float4 rv = srefs4[r];
    float dot = qx*rv.x + qy*rv.y + qz*rv.z;
    float d = (qq - 2.0f*dot) + rv.w;
    unsigned int ub = __float_as_uint(d);
    ub ^= ((unsigned int)((int)ub >> 31)) | 0x80000000u;
    unsigned long long kk = ((unsigned long long)ub << 32) | (unsigned int)r;
    if (kk < k2) {
      if (kk < k1) { k2 = k1; if (kk < k0) { k1 = k0; k0 = kk; } else k1 = kk; }
      else k2 = kk;
    }
  }
  int i0 = (int)(k0 & 0xffffffffu), i1 = (int)(k1 & 0xffffffffu), i2 = (int)(k2 & 0xffffffffu);
  const float* g1b = g1 + (size_t)b * S1_ * 64;
  const float4* p0 = (const float4*)(g1b + (size_t)i0 * 64);
  const float4* p1 = (const float4*)(g1b + (size_t)i1 * 64);
  const float4* p2 = (const float4*)(g1b + (size_t)i2 * 64);
  float fi[64];
  #pragma unroll
  for (int o = 0; o < 16; ++o) {
    float4 a = p0[o], bb = p1[o], cc = p2[o];
    fi[4*o+0] = (a.x + bb.x + cc.x) / 3.0f;
    fi[4*o+1] = (a.y + bb.y + cc.y) / 3.0f;
    fi[4*o+2] = (a.z + bb.z + cc.z) / 3.0f;
    fi[4*o+3] = (a.w + bb.w + cc.w) / 3.0f;
  }
  float h1r[32];
  #pragma unroll
  for (int k = 0; k < 32; ++k) h1r[k] = sb1[k];
  #pragma unroll
  for (int i = 0; i < 67; ++i) {
    float v = (i == 0) ? qx : (i == 1) ? qy : (i == 2) ? qz : fi[i-3];
    const float4* wrow = (const float4*)(sw1 + i*32);
    #pragma unroll
    for (int kq = 0; kq < 8; ++kq) {
      float4 wv = wrow[kq];
      h1r[4*kq+0] = fmaf(v, wv.x, h1r[4*kq+0]);
      h1r[4*kq+1] = fmaf(v, wv.y, h1r[4*kq+1]);
      h1r[4*kq+2] = fmaf(v, wv.z, h1r[4*kq+2]);
      h1r[4*kq+3] = fmaf(v, wv.w, h1r[4*kq+3]);
    }
  }
  #pragma unroll
  for (int k = 0; k < 32; ++k) h1r[k] = fmaxf(h1r[k], 0.0f);
  float h2r[32];
  #pragma unroll
  for (int m = 0; m < 32; ++m) h2r[m] = sb2[m];
  #pragma unroll
  for (int k = 0; k < 32; ++k) {
    float v = h1r[k];
    const float4* wrow = (const float4*)(sw2 + k*32);
    #pragma unroll
    for (int mq = 0; mq < 8; ++mq) {
      float4 wv = wrow[mq];
      h2r[4*mq+0] = fmaf(v, wv.x, h2r[4*mq+0]);
      h2r[4*mq+1] = fmaf(v, wv.y, h2r[4*mq+1]);
      h2r[4*mq+2] = fmaf(v, wv.z, h2r[4*mq+2]);
      h2r[4*mq+3] = fmaf(v, wv.w, h2r[4*mq+3]);
    }
  }
  float l0 = sfcb[0], l1 = sfcb[1];
  #pragma unroll
  for (int m = 0; m < 32; ++m) {
    l0 = fmaf(h2r[m], sfc[2*m+0], l0);
    l1 = fmaf(h2r[m], sfc[2*m+1], l1);
  }
  float mx = fmaxf(l0, l1);
  float s0 = l0 - mx, s1 = l1 - mx;
  float lg = logf(expf(s0) + expf(s1));
  float2 res; res.x = s0 - lg; res.y = s1 - lg;
  ((float2*)out)[(size_t)b * N_ + n] = res;
}

// ================= launch =================
extern "C" void kernel_launch(void* const* d_in, const int* in_sizes, int n_in,
                              void* d_out, int out_size, void* d_ws, size_t ws_size,
                              hipStream_t stream) {
  (void)in_sizes; (void)n_in; (void)out_size; (void)ws_size;
  const float* x     = (const float*)d_in[0];
  const float* sa1w1 = (const float*)d_in[1];
  const float* sa1b1 = (const float*)d_in[2];
  const float* sa1w2 = (const float*)d_in[3];
  const float* sa1b2 = (const float*)d_in[4];
  const float* sa2w1 = (const float*)d_in[5];
  const float* sa2b1 = (const float*)d_in[6];
  const float* sa2w2 = (const float*)d_in[7];
  const float* sa2b2 = (const float*)d_in[8];
  const float* fp1w1 = (const float*)d_in[9];
  const float* fp1b1 = (const float*)d_in[10];
  const float* fp1w2 = (const float*)d_in[11];
  const float* fp1b2 = (const float*)d_in[12];
  const float* fp2w1 = (const float*)d_in[13];
  const float* fp2b1 = (const float*)d_in[14];
  const float* fp2w2 = (const float*)d_in[15];
  const float* fp2b2 = (const float*)d_in[16];
  const float* fcw   = (const float*)d_in[17];
  const float* fcb   = (const float*)d_in[18];
  float* out = (float*)d_out;
  char* ws = (char*)d_ws;
  float4* xr4  = (float4*)(ws + OFF_XR4);
  float*  c1   = (float*)(ws + OFF_C1);
  float4* c1r4 = (float4*)(ws + OFF_C1R4);
  float*  c2   = (float*)(ws + OFF_C2);
  int*    nidx1= (int*)(ws + OFF_NIDX1);
  float*  f1   = (float*)(ws + OFF_F1);
  int*    nidx2= (int*)(ws + OFF_NIDX2);
  float*  f2   = (float*)(ws + OFF_F2);
  float*  g1   = (float*)(ws + OFF_G1);

  Samps smp;
  compute_samples(smp.s1, smp.s2);

  hipLaunchKernelGGL(k_prep,    dim3(B_*N_/256), dim3(256), 0, stream, x, xr4);
  hipLaunchKernelGGL(k_centers, dim3((B_*(S1_+S2_)+255)/256), dim3(256), 0, stream,
                     x, smp, c1, c1r4, c2);
  hipLaunchKernelGGL(k_knn,     dim3(B_*S1_/4), dim3(256), 0, stream, xr4, c1, nidx1, N_, 9);
  hipLaunchKernelGGL(k_sa1mlp,  dim3(B_*S1_/4), dim3(256), 0, stream,
                     x, nidx1, sa1w1, sa1b1, sa1w2, sa1b2, f1);
  hipLaunchKernelGGL(k_knn,     dim3(B_*S2_/4), dim3(256), 0, stream, c1r4, c2, nidx2, S1_, 7);
  hipLaunchKernelGGL(k_sa2mlp,  dim3(B_*S2_), dim3(256), 0, stream,
                     f1, nidx2, sa2w1, sa2b1, sa2w2, sa2b2, f2);
  hipLaunchKernelGGL(k_fp1,     dim3(B_*S1_/4), dim3(256), 0, stream,
                     c1, c2, f1, f2, fp1w1, fp1b1, fp1w2, fp1b2, g1);
  hipLaunchKernelGGL(k_fp2,     dim3(B_*N_/256), dim3(256), 0, stream,
                     x, c1, g1, fp2w1, fp2b1, fp2w2, fp2b2, fcw, fcb, out);
}

// Round 7
// 436.909 us; speedup vs baseline: 1.3204x; 1.0651x over previous
//
#include <hip/hip_runtime.h>
#include <stdint.h>

#define B_ 8
#define N_ 32768
#define S1_ 512
#define S2_ 128

// ---------------- workspace layout (bytes) ----------------
#define OFF_XR4   ((size_t)0)        // B*N float4 (xyz, rr)          4194304
#define OFF_C1    ((size_t)4194304)  // B*512*3 f32                     49152
#define OFF_C1R4  ((size_t)4243456)  // B*512 float4                    65536
#define OFF_C2    ((size_t)4308992)  // B*128*3 f32                     12288
#define OFF_NIDX1 ((size_t)4321280)  // B*512*32 i32                   524288
#define OFF_F1    ((size_t)4845568)  // B*512*64 f32                   524288
#define OFF_NIDX2 ((size_t)5369856)  // B*128*32 i32                   131072
#define OFF_F2    ((size_t)5500928)  // B*128*128 f32                  524288
#define OFF_G1    ((size_t)6025216)  // B*512*64 f32                   524288

struct Samps { int s1[S1_]; int s2[S2_]; };

// ================= host: replicate np.random.default_rng(0) =================
typedef unsigned __int128 u128;
struct RngState { u128 state, inc; bool has32; uint32_t saved; };

static uint64_t rng_next64(RngState* r) {
  const u128 MULT = ((u128)0x2360ed051fc65da4ULL << 64) | 0x4385df649fccf645ULL;
  r->state = r->state * MULT + r->inc;
  uint64_t hi = (uint64_t)(r->state >> 64), lo = (uint64_t)r->state;
  uint64_t xs = hi ^ lo;
  unsigned rot = (unsigned)(r->state >> 122);
  return (xs >> rot) | (xs << ((64u - rot) & 63u));
}
static uint32_t rng_next32(RngState* r) {
  if (r->has32) { r->has32 = false; return r->saved; }
  uint64_t v = rng_next64(r);
  r->has32 = true; r->saved = (uint32_t)(v >> 32);
  return (uint32_t)v;
}
static uint32_t rng_interval(RngState* r, uint32_t mx) {
  if (mx == 0) return 0;
  uint32_t mask = mx;
  mask |= mask >> 1; mask |= mask >> 2; mask |= mask >> 4;
  mask |= mask >> 8; mask |= mask >> 16;
  uint32_t v;
  while ((v = (rng_next32(r) & mask)) > mx) {}
  return v;
}
static void compute_samples(int* s1, int* s2) {
  uint32_t pool[4];
  uint32_t hc = 0x43b0d7e5u;
  auto hmix = [&hc](uint32_t v) -> uint32_t {
    v ^= hc; hc *= 0x931e8875u; v *= hc; v ^= v >> 16; return v;
  };
  auto mixf = [](uint32_t x, uint32_t y) -> uint32_t {
    uint32_t rr = (x * 0xca01f9ddu) ^ (y * 0x4973f715u);
    rr ^= rr >> 16; return rr;
  };
  pool[0] = hmix(0u); pool[1] = hmix(0u); pool[2] = hmix(0u); pool[3] = hmix(0u);
  for (int s = 0; s < 4; ++s)
    for (int d = 0; d < 4; ++d)
      if (s != d) pool[d] = mixf(pool[d], hmix(pool[s]));
  uint32_t hc2 = 0x8b51f9ddu;
  uint32_t w32[8];
  for (int i = 0; i < 8; ++i) {
    uint32_t dv = pool[i & 3];
    dv ^= hc2; hc2 *= 0x58f38dedu; dv *= hc2; dv ^= dv >> 16;
    w32[i] = dv;
  }
  uint64_t w64[4];
  for (int i = 0; i < 4; ++i) w64[i] = (uint64_t)w32[2*i] | ((uint64_t)w32[2*i+1] << 32);
  const u128 MULT = ((u128)0x2360ed051fc65da4ULL << 64) | 0x4385df649fccf645ULL;
  u128 initstate = ((u128)w64[0] << 64) | w64[1];
  u128 initseq   = ((u128)w64[2] << 64) | w64[3];
  RngState r; r.has32 = false; r.saved = 0;
  r.inc = (initseq << 1) | 1;
  r.state = 0;
  r.state = r.state * MULT + r.inc;
  r.state += initstate;
  r.state = r.state * MULT + r.inc;
  static int perm1[N_];
  for (int i = 0; i < N_; ++i) perm1[i] = i;
  for (int i = N_ - 1; i > 0; --i) {
    uint32_t j = rng_interval(&r, (uint32_t)i);
    int t = perm1[i]; perm1[i] = perm1[j]; perm1[j] = t;
  }
  for (int i = 0; i < S1_; ++i) s1[i] = perm1[i];
  int perm2[S1_];
  for (int i = 0; i < S1_; ++i) perm2[i] = i;
  for (int i = S1_ - 1; i > 0; --i) {
    uint32_t j = rng_interval(&r, (uint32_t)i);
    int t = perm2[i]; perm2[i] = perm2[j]; perm2[j] = t;
  }
  for (int i = 0; i < S2_; ++i) s2[i] = perm2[i];
}

// ================= device =================

__global__ void k_prep(const float* __restrict__ x, float4* __restrict__ xr4) {
  int t = blockIdx.x * blockDim.x + threadIdx.x;
  float a = x[3*t], b = x[3*t+1], c = x[3*t+2];
  xr4[t] = make_float4(a, b, c, a*a + b*b + c*c);
}

__global__ void k_centers(const float* __restrict__ x, Samps sm,
                          float* __restrict__ c1, float4* __restrict__ c1r4,
                          float* __restrict__ c2) {
  int t = blockIdx.x * blockDim.x + threadIdx.x;
  if (t < B_*S1_) {
    int b = t >> 9, c = t & (S1_-1);
    int sidx = sm.s1[c];
    const float* src = x + ((size_t)b*N_ + sidx)*3;
    float a = src[0], bb = src[1], cc = src[2];
    c1[(size_t)t*3+0] = a; c1[(size_t)t*3+1] = bb; c1[(size_t)t*3+2] = cc;
    c1r4[t] = make_float4(a, bb, cc, a*a + bb*bb + cc*cc);
  } else {
    int u = t - B_*S1_;
    if (u < B_*S2_) {
      int b = u >> 7, c = u & (S2_-1);
      int sidx = sm.s1[sm.s2[c]];
      const float* src = x + ((size_t)b*N_ + sidx)*3;
      c2[(size_t)u*3+0] = src[0]; c2[(size_t)u*3+1] = src[1]; c2[(size_t)u*3+2] = src[2];
    }
  }
}

// ---- kNN: one wave per query; sorted top-32 list (lane i = i-th best),
//      serial sorted-insert (expected ~250 inserts/query), bitonic prologue ----
#define KNN_KEY(RV, UB)                                                     \
  {                                                                         \
    float dot = qx*(RV).x + qy*(RV).y + qz*(RV).z;                          \
    float dd = (qq - 2.0f*dot) + (RV).w;                                    \
    (UB) = __float_as_uint(dd);                                             \
    (UB) ^= ((unsigned int)((int)(UB) >> 31)) | 0x80000000u;                \
  }

#define KNN_INSERT(UB, PBASE)                                               \
  {                                                                         \
    bool cand = ((UB) < T);                                                 \
    while (__any(cand)) {                                                   \
      unsigned long long bal = __ballot(cand);                              \
      int src = (int)__builtin_ctzll(bal);                                  \
      unsigned int ikd = (unsigned int)__shfl((int)(UB), src);              \
      unsigned int iki = (unsigned int)((PBASE) + src);                     \
      int pos = __popcll(__ballot(ld <= ikd));                              \
      unsigned int ud = (unsigned int)__shfl_up((int)ld, 1);                \
      unsigned int ui = (unsigned int)__shfl_up((int)li, 1);                \
      if (lane == pos)      { ld = ikd; li = iki; }                         \
      else if (lane > pos)  { ld = ud;  li = ui;  }                         \
      T = (unsigned int)__shfl((int)ld, 31);                                \
      cand = cand && ((UB) < T) && (lane != src);                           \
    }                                                                       \
  }

__launch_bounds__(256)
__global__ void k_knn(const float4* __restrict__ refs4, const float* __restrict__ qpts,
                      int* __restrict__ out_idx, int nrefs, int qshift) {
  const int tid = threadIdx.x, lane = tid & 63;
  const int q = blockIdx.x * 4 + (tid >> 6);
  const int b = q >> qshift;
  const float4* refs = refs4 + (size_t)b * nrefs;
  float qx = qpts[(size_t)q*3+0], qy = qpts[(size_t)q*3+1], qz = qpts[(size_t)q*3+2];
  float qq = qx*qx + qy*qy + qz*qz;
  unsigned int ld, li, T;
  {
    // prologue: first 64 refs via one bitonic sort (avoids 64 serial inserts at T=inf)
    float4 rv = refs[lane];
    unsigned int ub; KNN_KEY(rv, ub);
    unsigned long long key = ((unsigned long long)ub << 32) | (unsigned int)lane;
    #pragma unroll
    for (int k2 = 2; k2 <= 64; k2 <<= 1) {
      #pragma unroll
      for (int j = k2 >> 1; j >= 1; j >>= 1) {
        unsigned long long o = __shfl_xor(key, j);
        bool keepmin = (((lane & j) == 0) == ((lane & k2) == 0));
        if ((o < key) == keepmin) key = o;
      }
    }
    ld = (unsigned int)(key >> 32);
    li = (unsigned int)key;
    T = (unsigned int)__shfl((int)ld, 31);
  }
  {
    // rest of group 0 (refs 64..255)
    float4 r1 = refs[64 + lane];
    float4 r2 = refs[128 + lane];
    float4 r3 = refs[192 + lane];
    unsigned int u1, u2, u3;
    KNN_KEY(r1, u1); KNN_KEY(r2, u2); KNN_KEY(r3, u3);
    KNN_INSERT(u1, 64);
    KNN_INSERT(u2, 128);
    KNN_INSERT(u3, 192);
  }
  for (int g = 256; g + 255 < nrefs; g += 256) {
    float4 r0 = refs[g + lane];
    float4 r1 = refs[g + 64 + lane];
    float4 r2 = refs[g + 128 + lane];
    float4 r3 = refs[g + 192 + lane];
    unsigned int u0, u1, u2, u3;
    KNN_KEY(r0, u0); KNN_KEY(r1, u1); KNN_KEY(r2, u2); KNN_KEY(r3, u3);
    KNN_INSERT(u0, g);
    KNN_INSERT(u1, g + 64);
    KNN_INSERT(u2, g + 128);
    KNN_INSERT(u3, g + 192);
  }
  if (lane < 32) out_idx[(size_t)q*32 + lane] = (int)li;
}

// ---- SA1 MLP (3->64 relu ->64) + max over 32 neighbors; wave per center.
//      Wave-private LDS broadcast => NO barriers; pipelined neighbor gather. ----
__launch_bounds__(256)
__global__ void k_sa1mlp(const float* __restrict__ x, const int* __restrict__ nidx1,
                         const float* __restrict__ w1, const float* __restrict__ b1,
                         const float* __restrict__ w2, const float* __restrict__ b2,
                         float* __restrict__ f1) {
  __shared__ __align__(16) float hbuf[4][64];
  const int tid = threadIdx.x, wave = tid >> 6, lane = tid & 63;
  const int q = blockIdx.x * 4 + wave;
  const int b = q >> 9;
  const float* xb = x + (size_t)b * N_ * 3;
  float wc0 = w1[lane], wc1 = w1[64 + lane], wc2 = w1[128 + lane];
  float b1v = b1[lane], b2v = b2[lane];
  float w2c[64];
  #pragma unroll
  for (int h = 0; h < 64; ++h) w2c[h] = w2[h*64 + lane];
  const int* nb = nidx1 + (size_t)q * 32;
  int n0 = nb[0];
  float px = xb[3*n0], py = xb[3*n0+1], pz = xb[3*n0+2];
  float fm = -3.402823466e+38f;
  for (int j = 0; j < 32; ++j) {
    int n2 = nb[(j + 1) & 31];
    float nx = xb[3*n2], ny = xb[3*n2+1], nz = xb[3*n2+2];
    float h1 = fmaf(px, wc0, fmaf(py, wc1, fmaf(pz, wc2, b1v)));
    h1 = fmaxf(h1, 0.0f);
    hbuf[wave][lane] = h1;                    // wave-private: no barrier needed
    float acc = b2v;
    const float4* hv = (const float4*)(&hbuf[wave][0]);
    #pragma unroll
    for (int h4 = 0; h4 < 16; ++h4) {
      float4 v = hv[h4];
      acc = fmaf(v.x, w2c[4*h4+0], acc);
      acc = fmaf(v.y, w2c[4*h4+1], acc);
      acc = fmaf(v.z, w2c[4*h4+2], acc);
      acc = fmaf(v.w, w2c[4*h4+3], acc);
    }
    fm = fmaxf(fm, acc);
    px = nx; py = ny; pz = nz;
  }
  f1[(size_t)q*64 + lane] = fm;
}

// ---- SA2 MLP (64->128 relu ->128) + max; block(256) per center, split-K over s ----
__launch_bounds__(256)
__global__ void k_sa2mlp(const float* __restrict__ f1, const int* __restrict__ nidx2,
                         const float* __restrict__ w1, const float* __restrict__ b1,
                         const float* __restrict__ w2, const float* __restrict__ b2,
                         float* __restrict__ f2) {
  __shared__ __align__(16) float fin[64];
  __shared__ __align__(16) float h1s[128];
  __shared__ float ph[128];
  const int tid = threadIdx.x;
  const int s = tid >> 7, t = tid & 127;
  const int q = blockIdx.x;
  const int b = q >> 7;
  float w1r[32], w2r[64];
  #pragma unroll
  for (int i = 0; i < 32; ++i) w1r[i] = w1[(s*32 + i)*128 + t];
  #pragma unroll
  for (int h = 0; h < 64; ++h) w2r[h] = w2[(s*64 + h)*128 + t];
  float b1v = b1[t], b2v = b2[t];
  const int* nb = nidx2 + (size_t)q * 32;
  float fm = -3.402823466e+38f;
  for (int j = 0; j < 32; ++j) {
    int n = nb[j];
    __syncthreads();
    if (tid < 64) fin[tid] = f1[((size_t)b * S1_ + n)*64 + tid];
    __syncthreads();
    float p1 = 0.0f;
    const float4* fv = (const float4*)(fin + s*32);
    #pragma unroll
    for (int i4 = 0; i4 < 8; ++i4) {
      float4 v = fv[i4];
      p1 = fmaf(v.x, w1r[4*i4+0], p1);
      p1 = fmaf(v.y, w1r[4*i4+1], p1);
      p1 = fmaf(v.z, w1r[4*i4+2], p1);
      p1 = fmaf(v.w, w1r[4*i4+3], p1);
    }
    if (s) ph[t] = p1;
    __syncthreads();
    if (!s) h1s[t] = fmaxf(p1 + ph[t] + b1v, 0.0f);
    __syncthreads();
    float p2 = 0.0f;
    const float4* hv = (const float4*)(h1s + s*64);
    #pragma unroll
    for (int h4 = 0; h4 < 16; ++h4) {
      float4 v = hv[h4];
      p2 = fmaf(v.x, w2r[4*h4+0], p2);
      p2 = fmaf(v.y, w2r[4*h4+1], p2);
      p2 = fmaf(v.z, w2r[4*h4+2], p2);
      p2 = fmaf(v.w, w2r[4*h4+3], p2);
    }
    if (s) ph[t] = p2;
    __syncthreads();
    if (!s) fm = fmaxf(fm, p2 + ph[t] + b2v);
  }
  if (!s) f2[(size_t)q*128 + t] = fm;
}

// ---- FP1: kNN-3 over 128 refs + interp + MLP(192->64 relu ->64); wave per query ----
__launch_bounds__(256)
__global__ void k_fp1(const float* __restrict__ c1, const float* __restrict__ c2,
                      const float* __restrict__ f1, const float* __restrict__ f2,
                      const float* __restrict__ w1, const float* __restrict__ b1,
                      const float* __restrict__ w2, const float* __restrict__ b2,
                      float* __restrict__ g1) {
  __shared__ __align__(16) float sw1[192*64];
  __shared__ __align__(16) float sw2[64*64];
  __shared__ __align__(16) float sinp[4][192];
  __shared__ __align__(16) float sh1[4][64];
  __shared__ __align__(16) float4 srefs4[S2_];
  const int tid = threadIdx.x;
  const int wave = tid >> 6, lane = tid & 63;
  const int q = blockIdx.x * 4 + wave;
  const int b = q >> 9;
  for (int i = tid; i < 192*64; i += 256) sw1[i] = w1[i];
  for (int i = tid; i < 64*64; i += 256) sw2[i] = w2[i];
  if (tid < S2_) {
    const float* rp = c2 + ((size_t)b * S2_ + tid) * 3;
    float rx = rp[0], ry = rp[1], rz = rp[2];
    srefs4[tid] = make_float4(rx, ry, rz, rx*rx + ry*ry + rz*rz);
  }
  __syncthreads();
  float qx = c1[(size_t)q*3+0], qy = c1[(size_t)q*3+1], qz = c1[(size_t)q*3+2];
  float qq = qx*qx + qy*qy + qz*qz;
  unsigned long long ka, kb;
  {
    float4 rv = srefs4[lane];
    float dot = qx*rv.x + qy*rv.y + qz*rv.z;
    float d = (qq - 2.0f*dot) + rv.w;
    unsigned int ub = __float_as_uint(d);
    ub ^= ((unsigned int)((int)ub >> 31)) | 0x80000000u;
    ka = ((unsigned long long)ub << 32) | (unsigned int)lane;
    rv = srefs4[lane + 64];
    dot = qx*rv.x + qy*rv.y + qz*rv.z;
    d = (qq - 2.0f*dot) + rv.w;
    ub = __float_as_uint(d);
    ub ^= ((unsigned int)((int)ub >> 31)) | 0x80000000u;
    kb = ((unsigned long long)ub << 32) | (unsigned int)(lane + 64);
    if (kb < ka) { unsigned long long tt = ka; ka = kb; kb = tt; }
  }
  int nsel[3];
  #pragma unroll
  for (int r = 0; r < 3; ++r) {
    unsigned long long m = ka;
    #pragma unroll
    for (int s = 1; s < 64; s <<= 1) {
      unsigned long long o = __shfl_xor(m, s);
      if (o < m) m = o;
    }
    nsel[r] = (int)(m & 0xffffffffu);
    if (ka == m) { ka = kb; kb = ~0ULL; }
  }
  const float* f2b = f2 + (size_t)b * S2_ * 128;
  sinp[wave][lane] = f1[(size_t)q*64 + lane];
  {
    float a0 = f2b[(size_t)nsel[0]*128 + lane];
    float a1 = f2b[(size_t)nsel[1]*128 + lane];
    float a2 = f2b[(size_t)nsel[2]*128 + lane];
    sinp[wave][64 + lane] = (a0 + a1 + a2) / 3.0f;
    a0 = f2b[(size_t)nsel[0]*128 + 64 + lane];
    a1 = f2b[(size_t)nsel[1]*128 + 64 + lane];
    a2 = f2b[(size_t)nsel[2]*128 + 64 + lane];
    sinp[wave][128 + lane] = (a0 + a1 + a2) / 3.0f;
  }
  __syncthreads();
  float acc = b1[lane];
  const float4* sv = (const float4*)(&sinp[wave][0]);
  #pragma unroll
  for (int i4 = 0; i4 < 48; ++i4) {
    float4 v = sv[i4];
    acc = fmaf(v.x, sw1[(4*i4+0)*64 + lane], acc);
    acc = fmaf(v.y, sw1[(4*i4+1)*64 + lane], acc);
    acc = fmaf(v.z, sw1[(4*i4+2)*64 + lane], acc);
    acc = fmaf(v.w, sw1[(4*i4+3)*64 + lane], acc);
  }
  sh1[wave][lane] = fmaxf(acc, 0.0f);
  __syncthreads();
  float acc2 = b2[lane];
  const float4* hv = (const float4*)(&sh1[wave][0]);
  #pragma unroll
  for (int h4 = 0; h4 < 16; ++h4) {
    float4 v = hv[h4];
    acc2 = fmaf(v.x, sw2[(4*h4+0)*64 + lane], acc2);
    acc2 = fmaf(v.y, sw2[(4*h4+1)*64 + lane], acc2);
    acc2 = fmaf(v.z, sw2[(4*h4+2)*64 + lane], acc2);
    acc2 = fmaf(v.w, sw2[(4*h4+3)*64 + lane], acc2);
  }
  g1[(size_t)q*64 + lane] = acc2;
}

// ---- FP2: kNN-3 over 512 refs + interp + MLP(67->32 relu ->32) + FC + log_softmax ----
// Scan rewritten: f32 strict-< branchless top-3 (exact (d,idx) lexicographic via
// ascending-index scan), hand-unrolled x4 with hoisted LDS loads.
#define FP2_PROC(RV, R)                                                     \
  {                                                                         \
    float dot = qx*(RV).x + qy*(RV).y + qz*(RV).z;                          \
    float dd = (qq - 2.0f*dot) + (RV).w;                                    \
    bool c0 = dd < d0, c1 = dd < d1, c2 = dd < d2;                          \
    i2 = c1 ? i1 : (c2 ? (R) : i2);                                         \
    d2 = c1 ? d1 : fminf(d2, dd);                                           \
    i1 = c0 ? i0 : (c1 ? (R) : i1);                                         \
    d1 = c0 ? d0 : fminf(d1, dd);                                           \
    i0 = c0 ? (R) : i0;                                                     \
    d0 = fminf(d0, dd);                                                     \
  }

__launch_bounds__(256)
__global__ void k_fp2(const float* __restrict__ x, const float* __restrict__ c1,
                      const float* __restrict__ g1,
                      const float* __restrict__ w1, const float* __restrict__ b1,
                      const float* __restrict__ w2, const float* __restrict__ b2,
                      const float* __restrict__ fcw, const float* __restrict__ fcb,
                      float* __restrict__ out) {
  __shared__ __align__(16) float4 srefs4[S1_];
  __shared__ __align__(16) float sw1[67*32];
  __shared__ __align__(16) float sw2[32*32];
  __shared__ __align__(16) float sfc[64];
  __shared__ float sb1[32], sb2[32], sfcb[2];
  const int tid = threadIdx.x;
  const int b = blockIdx.x >> 7;
  const int n = ((blockIdx.x & 127) << 8) + tid;
  const float* c1b = c1 + (size_t)b * S1_ * 3;
  for (int i = tid; i < S1_; i += 256) {
    float rx = c1b[3*i], ry = c1b[3*i+1], rz = c1b[3*i+2];
    srefs4[i] = make_float4(rx, ry, rz, rx*rx + ry*ry + rz*rz);
  }
  for (int i = tid; i < 67*32; i += 256) sw1[i] = w1[i];
  for (int i = tid; i < 32*32; i += 256) sw2[i] = w2[i];
  if (tid < 64) sfc[tid] = fcw[tid];
  if (tid < 32) { sb1[tid] = b1[tid]; sb2[tid] = b2[tid]; }
  if (tid < 2) sfcb[tid] = fcb[tid];
  __syncthreads();
  const float* xb = x + (size_t)b * N_ * 3;
  float qx = xb[3*n], qy = xb[3*n+1], qz = xb[3*n+2];
  float qq = qx*qx + qy*qy + qz*qz;
  float d0 = 3.402823466e+38f, d1 = d0, d2 = d0;
  int i0 = 0, i1 = 0, i2 = 0;
  for (int r = 0; r < S1_; r += 4) {
    float4 ra = srefs4[r+0];
    float4 rb = srefs4[r+1];
    float4 rc = srefs4[r+2];
    float4 rd = srefs4[r+3];
    FP2_PROC(ra, r+0);
    FP2_PROC(rb, r+1);
    FP2_PROC(rc, r+2);
    FP2_PROC(rd, r+3);
  }
  const float* g1b = g1 + (size_t)b * S1_ * 64;
  const float4* p0 = (const float4*)(g1b + (size_t)i0 * 64);
  const float4* p1 = (const float4*)(g1b + (size_t)i1 * 64);
  const float4* p2 = (const float4*)(g1b + (size_t)i2 * 64);
  float fi[64];
  #pragma unroll
  for (int o = 0; o < 16; ++o) {
    float4 a = p0[o], bb = p1[o], cc = p2[o];
    fi[4*o+0] = (a.x + bb.x + cc.x) / 3.0f;
    fi[4*o+1] = (a.y + bb.y + cc.y) / 3.0f;
    fi[4*o+2] = (a.z + bb.z + cc.z) / 3.0f;
    fi[4*o+3] = (a.w + bb.w + cc.w) / 3.0f;
  }
  float h1r[32];
  #pragma unroll
  for (int k = 0; k < 32; ++k) h1r[k] = sb1[k];
  #pragma unroll
  for (int i = 0; i < 67; ++i) {
    float v = (i == 0) ? qx : (i == 1) ? qy : (i == 2) ? qz : fi[i-3];
    const float4* wrow = (const float4*)(sw1 + i*32);
    #pragma unroll
    for (int kq = 0; kq < 8; ++kq) {
      float4 wv = wrow[kq];
      h1r[4*kq+0] = fmaf(v, wv.x, h1r[4*kq+0]);
      h1r[4*kq+1] = fmaf(v, wv.y, h1r[4*kq+1]);
      h1r[4*kq+2] = fmaf(v, wv.z, h1r[4*kq+2]);
      h1r[4*kq+3] = fmaf(v, wv.w, h1r[4*kq+3]);
    }
  }
  #pragma unroll
  for (int k = 0; k < 32; ++k) h1r[k] = fmaxf(h1r[k], 0.0f);
  float h2r[32];
  #pragma unroll
  for (int m = 0; m < 32; ++m) h2r[m] = sb2[m];
  #pragma unroll
  for (int k = 0; k < 32; ++k) {
    float v = h1r[k];
    const float4* wrow = (const float4*)(sw2 + k*32);
    #pragma unroll
    for (int mq = 0; mq < 8; ++mq) {
      float4 wv = wrow[mq];
      h2r[4*mq+0] = fmaf(v, wv.x, h2r[4*mq+0]);
      h2r[4*mq+1] = fmaf(v, wv.y, h2r[4*mq+1]);
      h2r[4*mq+2] = fmaf(v, wv.z, h2r[4*mq+2]);
      h2r[4*mq+3] = fmaf(v, wv.w, h2r[4*mq+3]);
    }
  }
  float l0 = sfcb[0], l1 = sfcb[1];
  #pragma unroll
  for (int m = 0; m < 32; ++m) {
    l0 = fmaf(h2r[m], sfc[2*m+0], l0);
    l1 = fmaf(h2r[m], sfc[2*m+1], l1);
  }
  float mx = fmaxf(l0, l1);
  float s0 = l0 - mx, s1 = l1 - mx;
  float lg = logf(expf(s0) + expf(s1));
  float2 res; res.x = s0 - lg; res.y = s1 - lg;
  ((float2*)out)[(size_t)b * N_ + n] = res;
}

// ================= launch =================
extern "C" void kernel_launch(void* const* d_in, const int* in_sizes, int n_in,
                              void* d_out, int out_size, void* d_ws, size_t ws_size,
                              hipStream_t stream) {
  (void)in_sizes; (void)n_in; (void)out_size; (void)ws_size;
  const float* x     = (const float*)d_in[0];
  const float* sa1w1 = (const float*)d_in[1];
  const float* sa1b1 = (const float*)d_in[2];
  const float* sa1w2 = (const float*)d_in[3];
  const float* sa1b2 = (const float*)d_in[4];
  const float* sa2w1 = (const float*)d_in[5];
  const float* sa2b1 = (const float*)d_in[6];
  const float* sa2w2 = (const float*)d_in[7];
  const float* sa2b2 = (const float*)d_in[8];
  const float* fp1w1 = (const float*)d_in[9];
  const float* fp1b1 = (const float*)d_in[10];
  const float* fp1w2 = (const float*)d_in[11];
  const float* fp1b2 = (const float*)d_in[12];
  const float* fp2w1 = (const float*)d_in[13];
  const float* fp2b1 = (const float*)d_in[14];
  const float* fp2w2 = (const float*)d_in[15];
  const float* fp2b2 = (const float*)d_in[16];
  const float* fcw   = (const float*)d_in[17];
  const float* fcb   = (const float*)d_in[18];
  float* out = (float*)d_out;
  char* ws = (char*)d_ws;
  float4* xr4  = (float4*)(ws + OFF_XR4);
  float*  c1   = (float*)(ws + OFF_C1);
  float4* c1r4 = (float4*)(ws + OFF_C1R4);
  float*  c2   = (float*)(ws + OFF_C2);
  int*    nidx1= (int*)(ws + OFF_NIDX1);
  float*  f1   = (float*)(ws + OFF_F1);
  int*    nidx2= (int*)(ws + OFF_NIDX2);
  float*  f2   = (float*)(ws + OFF_F2);
  float*  g1   = (float*)(ws + OFF_G1);

  Samps smp;
  compute_samples(smp.s1, smp.s2);

  hipLaunchKernelGGL(k_prep,    dim3(B_*N_/256), dim3(256), 0, stream, x, xr4);
  hipLaunchKernelGGL(k_centers, dim3((B_*(S1_+S2_)+255)/256), dim3(256), 0, stream,
                     x, smp, c1, c1r4, c2);
  hipLaunchKernelGGL(k_knn,     dim3(B_*S1_/4), dim3(256), 0, stream, xr4, c1, nidx1, N_, 9);
  hipLaunchKernelGGL(k_sa1mlp,  dim3(B_*S1_/4), dim3(256), 0, stream,
                     x, nidx1, sa1w1, sa1b1, sa1w2, sa1b2, f1);
  hipLaunchKernelGGL(k_knn,     dim3(B_*S2_/4), dim3(256), 0, stream, c1r4, c2, nidx2, S1_, 7);
  hipLaunchKernelGGL(k_sa2mlp,  dim3(B_*S2_), dim3(256), 0, stream,
                     f1, nidx2, sa2w1, sa2b1, sa2w2, sa2b2, f2);
  hipLaunchKernelGGL(k_fp1,     dim3(B_*S1_/4), dim3(256), 0, stream,
                     c1, c2, f1, f2, fp1w1, fp1b1, fp1w2, fp1b2, g1);
  hipLaunchKernelGGL(k_fp2,     dim3(B_*N_/256), dim3(256), 0, stream,
                     x, c1, g1, fp2w1, fp2b1, fp2w2, fp2b2, fcw, fcb, out);
}

// Round 10
// 402.960 us; speedup vs baseline: 1.4317x; 1.0842x over previous
//
#include <hip/hip_runtime.h>
#include <stdint.h>

#define B_ 8
#define N_ 32768
#define S1_ 512
#define S2_ 128

// ---------------- workspace layout (bytes) ----------------
#define OFF_XR4   ((size_t)0)        // B*N float4 (xyz, rr)          4194304
#define OFF_C1    ((size_t)4194304)  // B*512*3 f32                     49152
#define OFF_C1R4  ((size_t)4243456)  // B*512 float4                    65536
#define OFF_C2    ((size_t)4308992)  // B*128*3 f32                     12288
#define OFF_NIDX1 ((size_t)4321280)  // B*512*32 i32                   524288
#define OFF_F1    ((size_t)4845568)  // B*512*64 f32                   524288
#define OFF_NIDX2 ((size_t)5369856)  // B*128*32 i32                   131072
#define OFF_F2    ((size_t)5500928)  // B*128*128 f32                  524288
#define OFF_G1    ((size_t)6025216)  // B*512*64 f32                   524288

struct Samps { int s1[S1_]; int s2[S2_]; };

// ================= host: replicate np.random.default_rng(0) =================
typedef unsigned __int128 u128;
struct RngState { u128 state, inc; bool has32; uint32_t saved; };

static uint64_t rng_next64(RngState* r) {
  const u128 MULT = ((u128)0x2360ed051fc65da4ULL << 64) | 0x4385df649fccf645ULL;
  r->state = r->state * MULT + r->inc;
  uint64_t hi = (uint64_t)(r->state >> 64), lo = (uint64_t)r->state;
  uint64_t xs = hi ^ lo;
  unsigned rot = (unsigned)(r->state >> 122);
  return (xs >> rot) | (xs << ((64u - rot) & 63u));
}
static uint32_t rng_next32(RngState* r) {
  if (r->has32) { r->has32 = false; return r->saved; }
  uint64_t v = rng_next64(r);
  r->has32 = true; r->saved = (uint32_t)(v >> 32);
  return (uint32_t)v;
}
static uint32_t rng_interval(RngState* r, uint32_t mx) {
  if (mx == 0) return 0;
  uint32_t mask = mx;
  mask |= mask >> 1; mask |= mask >> 2; mask |= mask >> 4;
  mask |= mask >> 8; mask |= mask >> 16;
  uint32_t v;
  while ((v = (rng_next32(r) & mask)) > mx) {}
  return v;
}
static void compute_samples(int* s1, int* s2) {
  uint32_t pool[4];
  uint32_t hc = 0x43b0d7e5u;
  auto hmix = [&hc](uint32_t v) -> uint32_t {
    v ^= hc; hc *= 0x931e8875u; v *= hc; v ^= v >> 16; return v;
  };
  auto mixf = [](uint32_t x, uint32_t y) -> uint32_t {
    uint32_t rr = (x * 0xca01f9ddu) ^ (y * 0x4973f715u);
    rr ^= rr >> 16; return rr;
  };
  pool[0] = hmix(0u); pool[1] = hmix(0u); pool[2] = hmix(0u); pool[3] = hmix(0u);
  for (int s = 0; s < 4; ++s)
    for (int d = 0; d < 4; ++d)
      if (s != d) pool[d] = mixf(pool[d], hmix(pool[s]));
  uint32_t hc2 = 0x8b51f9ddu;
  uint32_t w32[8];
  for (int i = 0; i < 8; ++i) {
    uint32_t dv = pool[i & 3];
    dv ^= hc2; hc2 *= 0x58f38dedu; dv *= hc2; dv ^= dv >> 16;
    w32[i] = dv;
  }
  uint64_t w64[4];
  for (int i = 0; i < 4; ++i) w64[i] = (uint64_t)w32[2*i] | ((uint64_t)w32[2*i+1] << 32);
  const u128 MULT = ((u128)0x2360ed051fc65da4ULL << 64) | 0x4385df649fccf645ULL;
  u128 initstate = ((u128)w64[0] << 64) | w64[1];
  u128 initseq   = ((u128)w64[2] << 64) | w64[3];
  RngState r; r.has32 = false; r.saved = 0;
  r.inc = (initseq << 1) | 1;
  r.state = 0;
  r.state = r.state * MULT + r.inc;
  r.state += initstate;
  r.state = r.state * MULT + r.inc;
  static int perm1[N_];
  for (int i = 0; i < N_; ++i) perm1[i] = i;
  for (int i = N_ - 1; i > 0; --i) {
    uint32_t j = rng_interval(&r, (uint32_t)i);
    int t = perm1[i]; perm1[i] = perm1[j]; perm1[j] = t;
  }
  for (int i = 0; i < S1_; ++i) s1[i] = perm1[i];
  int perm2[S1_];
  for (int i = 0; i < S1_; ++i) perm2[i] = i;
  for (int i = S1_ - 1; i > 0; --i) {
    uint32_t j = rng_interval(&r, (uint32_t)i);
    int t = perm2[i]; perm2[i] = perm2[j]; perm2[j] = t;
  }
  for (int i = 0; i < S2_; ++i) s2[i] = perm2[i];
}

// ================= device =================

__global__ void k_prep(const float* __restrict__ x, float4* __restrict__ xr4) {
  int t = blockIdx.x * blockDim.x + threadIdx.x;
  float a = x[3*t], b = x[3*t+1], c = x[3*t+2];
  xr4[t] = make_float4(a, b, c, a*a + b*b + c*c);
}

__global__ void k_centers(const float* __restrict__ x, Samps sm,
                          float* __restrict__ c1, float4* __restrict__ c1r4,
                          float* __restrict__ c2) {
  int t = blockIdx.x * blockDim.x + threadIdx.x;
  if (t < B_*S1_) {
    int b = t >> 9, c = t & (S1_-1);
    int sidx = sm.s1[c];
    const float* src = x + ((size_t)b*N_ + sidx)*3;
    float a = src[0], bb = src[1], cc = src[2];
    c1[(size_t)t*3+0] = a; c1[(size_t)t*3+1] = bb; c1[(size_t)t*3+2] = cc;
    c1r4[t] = make_float4(a, bb, cc, a*a + bb*bb + cc*cc);
  } else {
    int u = t - B_*S1_;
    if (u < B_*S2_) {
      int b = u >> 7, c = u & (S2_-1);
      int sidx = sm.s1[sm.s2[c]];
      const float* src = x + ((size_t)b*N_ + sidx)*3;
      c2[(size_t)u*3+0] = src[0]; c2[(size_t)u*3+1] = src[1]; c2[(size_t)u*3+2] = src[2];
    }
  }
}

// ---- kNN: one wave per query; sorted top-32 list (lane i = i-th best),
//      serial sorted-insert (expected ~250 inserts/query), bitonic prologue ----
#define KNN_KEY(RV, UB)                                                     \
  {                                                                         \
    float dot = qx*(RV).x + qy*(RV).y + qz*(RV).z;                          \
    float dd = (qq - 2.0f*dot) + (RV).w;                                    \
    (UB) = __float_as_uint(dd);                                             \
    (UB) ^= ((unsigned int)((int)(UB) >> 31)) | 0x80000000u;                \
  }

#define KNN_INSERT(UB, PBASE)                                               \
  {                                                                         \
    bool cand = ((UB) < T);                                                 \
    while (__any(cand)) {                                                   \
      unsigned long long bal = __ballot(cand);                              \
      int src = (int)__builtin_ctzll(bal);                                  \
      unsigned int ikd = (unsigned int)__shfl((int)(UB), src);              \
      unsigned int iki = (unsigned int)((PBASE) + src);                     \
      int pos = __popcll(__ballot(ld <= ikd));                              \
      unsigned int ud = (unsigned int)__shfl_up((int)ld, 1);                \
      unsigned int ui = (unsigned int)__shfl_up((int)li, 1);                \
      if (lane == pos)      { ld = ikd; li = iki; }                         \
      else if (lane > pos)  { ld = ud;  li = ui;  }                         \
      T = (unsigned int)__shfl((int)ld, 31);                                \
      cand = cand && ((UB) < T) && (lane != src);                           \
    }                                                                       \
  }

__launch_bounds__(256)
__global__ void k_knn(const float4* __restrict__ refs4, const float* __restrict__ qpts,
                      int* __restrict__ out_idx, int nrefs, int qshift) {
  const int tid = threadIdx.x, lane = tid & 63;
  const int q = blockIdx.x * 4 + (tid >> 6);
  const int b = q >> qshift;
  const float4* refs = refs4 + (size_t)b * nrefs;
  float qx = qpts[(size_t)q*3+0], qy = qpts[(size_t)q*3+1], qz = qpts[(size_t)q*3+2];
  float qq = qx*qx + qy*qy + qz*qz;
  unsigned int ld, li, T;
  {
    // prologue: first 64 refs via one bitonic sort (avoids 64 serial inserts at T=inf)
    float4 rv = refs[lane];
    unsigned int ub; KNN_KEY(rv, ub);
    unsigned long long key = ((unsigned long long)ub << 32) | (unsigned int)lane;
    #pragma unroll
    for (int k2 = 2; k2 <= 64; k2 <<= 1) {
      #pragma unroll
      for (int j = k2 >> 1; j >= 1; j >>= 1) {
        unsigned long long o = __shfl_xor(key, j);
        bool keepmin = (((lane & j) == 0) == ((lane & k2) == 0));
        if ((o < key) == keepmin) key = o;
      }
    }
    ld = (unsigned int)(key >> 32);
    li = (unsigned int)key;
    T = (unsigned int)__shfl((int)ld, 31);
  }
  {
    // rest of group 0 (refs 64..255)
    float4 r1 = refs[64 + lane];
    float4 r2 = refs[128 + lane];
    float4 r3 = refs[192 + lane];
    unsigned int u1, u2, u3;
    KNN_KEY(r1, u1); KNN_KEY(r2, u2); KNN_KEY(r3, u3);
    KNN_INSERT(u1, 64);
    KNN_INSERT(u2, 128);
    KNN_INSERT(u3, 192);
  }
  for (int g = 256; g + 255 < nrefs; g += 256) {
    float4 r0 = refs[g + lane];
    float4 r1 = refs[g + 64 + lane];
    float4 r2 = refs[g + 128 + lane];
    float4 r3 = refs[g + 192 + lane];
    unsigned int u0, u1, u2, u3;
    KNN_KEY(r0, u0); KNN_KEY(r1, u1); KNN_KEY(r2, u2); KNN_KEY(r3, u3);
    KNN_INSERT(u0, g);
    KNN_INSERT(u1, g + 64);
    KNN_INSERT(u2, g + 128);
    KNN_INSERT(u3, g + 192);
  }
  if (lane < 32) out_idx[(size_t)q*32 + lane] = (int)li;
}

// ---- SA1 MLP (3->64 relu ->64) + max over 32 neighbors; wave per center.
//      Wave-private LDS broadcast => NO barriers; pipelined neighbor gather. ----
__launch_bounds__(256)
__global__ void k_sa1mlp(const float* __restrict__ x, const int* __restrict__ nidx1,
                         const float* __restrict__ w1, const float* __restrict__ b1,
                         const float* __restrict__ w2, const float* __restrict__ b2,
                         float* __restrict__ f1) {
  __shared__ __align__(16) float hbuf[4][64];
  const int tid = threadIdx.x, wave = tid >> 6, lane = tid & 63;
  const int q = blockIdx.x * 4 + wave;
  const int b = q >> 9;
  const float* xb = x + (size_t)b * N_ * 3;
  float wc0 = w1[lane], wc1 = w1[64 + lane], wc2 = w1[128 + lane];
  float b1v = b1[lane], b2v = b2[lane];
  float w2c[64];
  #pragma unroll
  for (int h = 0; h < 64; ++h) w2c[h] = w2[h*64 + lane];
  const int* nb = nidx1 + (size_t)q * 32;
  int n0 = nb[0];
  float px = xb[3*n0], py = xb[3*n0+1], pz = xb[3*n0+2];
  float fm = -3.402823466e+38f;
  for (int j = 0; j < 32; ++j) {
    int n2 = nb[(j + 1) & 31];
    float nx = xb[3*n2], ny = xb[3*n2+1], nz = xb[3*n2+2];
    float h1 = fmaf(px, wc0, fmaf(py, wc1, fmaf(pz, wc2, b1v)));
    h1 = fmaxf(h1, 0.0f);
    hbuf[wave][lane] = h1;                    // wave-private: no barrier needed
    float acc = b2v;
    const float4* hv = (const float4*)(&hbuf[wave][0]);
    #pragma unroll
    for (int h4 = 0; h4 < 16; ++h4) {
      float4 v = hv[h4];
      acc = fmaf(v.x, w2c[4*h4+0], acc);
      acc = fmaf(v.y, w2c[4*h4+1], acc);
      acc = fmaf(v.z, w2c[4*h4+2], acc);
      acc = fmaf(v.w, w2c[4*h4+3], acc);
    }
    fm = fmaxf(fm, acc);
    px = nx; py = ny; pz = nz;
  }
  f1[(size_t)q*64 + lane] = fm;
}

// ---- SA2 MLP (64->128 relu ->128) + max; block(256) per center, split-K over s ----
__launch_bounds__(256)
__global__ void k_sa2mlp(const float* __restrict__ f1, const int* __restrict__ nidx2,
                         const float* __restrict__ w1, const float* __restrict__ b1,
                         const float* __restrict__ w2, const float* __restrict__ b2,
                         float* __restrict__ f2) {
  __shared__ __align__(16) float fin[64];
  __shared__ __align__(16) float h1s[128];
  __shared__ float ph[128];
  const int tid = threadIdx.x;
  const int s = tid >> 7, t = tid & 127;
  const int q = blockIdx.x;
  const int b = q >> 7;
  float w1r[32], w2r[64];
  #pragma unroll
  for (int i = 0; i < 32; ++i) w1r[i] = w1[(s*32 + i)*128 + t];
  #pragma unroll
  for (int h = 0; h < 64; ++h) w2r[h] = w2[(s*64 + h)*128 + t];
  float b1v = b1[t], b2v = b2[t];
  const int* nb = nidx2 + (size_t)q * 32;
  float fm = -3.402823466e+38f;
  for (int j = 0; j < 32; ++j) {
    int n = nb[j];
    __syncthreads();
    if (tid < 64) fin[tid] = f1[((size_t)b * S1_ + n)*64 + tid];
    __syncthreads();
    float p1 = 0.0f;
    const float4* fv = (const float4*)(fin + s*32);
    #pragma unroll
    for (int i4 = 0; i4 < 8; ++i4) {
      float4 v = fv[i4];
      p1 = fmaf(v.x, w1r[4*i4+0], p1);
      p1 = fmaf(v.y, w1r[4*i4+1], p1);
      p1 = fmaf(v.z, w1r[4*i4+2], p1);
      p1 = fmaf(v.w, w1r[4*i4+3], p1);
    }
    if (s) ph[t] = p1;
    __syncthreads();
    if (!s) h1s[t] = fmaxf(p1 + ph[t] + b1v, 0.0f);
    __syncthreads();
    float p2 = 0.0f;
    const float4* hv = (const float4*)(h1s + s*64);
    #pragma unroll
    for (int h4 = 0; h4 < 16; ++h4) {
      float4 v = hv[h4];
      p2 = fmaf(v.x, w2r[4*h4+0], p2);
      p2 = fmaf(v.y, w2r[4*h4+1], p2);
      p2 = fmaf(v.z, w2r[4*h4+2], p2);
      p2 = fmaf(v.w, w2r[4*h4+3], p2);
    }
    if (s) ph[t] = p2;
    __syncthreads();
    if (!s) fm = fmaxf(fm, p2 + ph[t] + b2v);
  }
  if (!s) f2[(size_t)q*128 + t] = fm;
}

// ---- FP1: kNN-3 over 128 refs + interp + MLP(192->64 relu ->64); wave per query ----
__launch_bounds__(256)
__global__ void k_fp1(const float* __restrict__ c1, const float* __restrict__ c2,
                      const float* __restrict__ f1, const float* __restrict__ f2,
                      const float* __restrict__ w1, const float* __restrict__ b1,
                      const float* __restrict__ w2, const float* __restrict__ b2,
                      float* __restrict__ g1) {
  __shared__ __align__(16) float sw1[192*64];
  __shared__ __align__(16) float sw2[64*64];
  __shared__ __align__(16) float sinp[4][192];
  __shared__ __align__(16) float sh1[4][64];
  __shared__ __align__(16) float4 srefs4[S2_];
  const int tid = threadIdx.x;
  const int wave = tid >> 6, lane = tid & 63;
  const int q = blockIdx.x * 4 + wave;
  const int b = q >> 9;
  for (int i = tid; i < 192*64; i += 256) sw1[i] = w1[i];
  for (int i = tid; i < 64*64; i += 256) sw2[i] = w2[i];
  if (tid < S2_) {
    const float* rp = c2 + ((size_t)b * S2_ + tid) * 3;
    float rx = rp[0], ry = rp[1], rz = rp[2];
    srefs4[tid] = make_float4(rx, ry, rz, rx*rx + ry*ry + rz*rz);
  }
  __syncthreads();
  float qx = c1[(size_t)q*3+0], qy = c1[(size_t)q*3+1], qz = c1[(size_t)q*3+2];
  float qq = qx*qx + qy*qy + qz*qz;
  unsigned long long ka, kb;
  {
    float4 rv = srefs4[lane];
    float dot = qx*rv.x + qy*rv.y + qz*rv.z;
    float d = (qq - 2.0f*dot) + rv.w;
    unsigned int ub = __float_as_uint(d);
    ub ^= ((unsigned int)((int)ub >> 31)) | 0x80000000u;
    ka = ((unsigned long long)ub << 32) | (unsigned int)lane;
    rv = srefs4[lane + 64];
    dot = qx*rv.x + qy*rv.y + qz*rv.z;
    d = (qq - 2.0f*dot) + rv.w;
    ub = __float_as_uint(d);
    ub ^= ((unsigned int)((int)ub >> 31)) | 0x80000000u;
    kb = ((unsigned long long)ub << 32) | (unsigned int)(lane + 64);
    if (kb < ka) { unsigned long long tt = ka; ka = kb; kb = tt; }
  }
  int nsel[3];
  #pragma unroll
  for (int r = 0; r < 3; ++r) {
    unsigned long long m = ka;
    #pragma unroll
    for (int s = 1; s < 64; s <<= 1) {
      unsigned long long o = __shfl_xor(m, s);
      if (o < m) m = o;
    }
    nsel[r] = (int)(m & 0xffffffffu);
    if (ka == m) { ka = kb; kb = ~0ULL; }
  }
  const float* f2b = f2 + (size_t)b * S2_ * 128;
  sinp[wave][lane] = f1[(size_t)q*64 + lane];
  {
    float a0 = f2b[(size_t)nsel[0]*128 + lane];
    float a1 = f2b[(size_t)nsel[1]*128 + lane];
    float a2 = f2b[(size_t)nsel[2]*128 + lane];
    sinp[wave][64 + lane] = (a0 + a1 + a2) / 3.0f;
    a0 = f2b[(size_t)nsel[0]*128 + 64 + lane];
    a1 = f2b[(size_t)nsel[1]*128 + 64 + lane];
    a2 = f2b[(size_t)nsel[2]*128 + 64 + lane];
    sinp[wave][128 + lane] = (a0 + a1 + a2) / 3.0f;
  }
  __syncthreads();
  float acc = b1[lane];
  const float4* sv = (const float4*)(&sinp[wave][0]);
  #pragma unroll
  for (int i4 = 0; i4 < 48; ++i4) {
    float4 v = sv[i4];
    acc = fmaf(v.x, sw1[(4*i4+0)*64 + lane], acc);
    acc = fmaf(v.y, sw1[(4*i4+1)*64 + lane], acc);
    acc = fmaf(v.z, sw1[(4*i4+2)*64 + lane], acc);
    acc = fmaf(v.w, sw1[(4*i4+3)*64 + lane], acc);
  }
  sh1[wave][lane] = fmaxf(acc, 0.0f);
  __syncthreads();
  float acc2 = b2[lane];
  const float4* hv = (const float4*)(&sh1[wave][0]);
  #pragma unroll
  for (int h4 = 0; h4 < 16; ++h4) {
    float4 v = hv[h4];
    acc2 = fmaf(v.x, sw2[(4*h4+0)*64 + lane], acc2);
    acc2 = fmaf(v.y, sw2[(4*h4+1)*64 + lane], acc2);
    acc2 = fmaf(v.z, sw2[(4*h4+2)*64 + lane], acc2);
    acc2 = fmaf(v.w, sw2[(4*h4+3)*64 + lane], acc2);
  }
  g1[(size_t)q*64 + lane] = acc2;
}

// ---- FP2: kNN-3 over 512 refs + interp + MLP(67->32 relu ->32) + FC + log_softmax ----
// Round-7 scan: refs streamed from GLOBAL c1r4 (wave-uniform addr, L1-resident)
// -> no LDS-pipe floor, no srefs4 staging. Interp folded into w1 loop (no fi[64]).
// /3.0f -> *(1/3) (no div sequences).
#define FP2_PROC(RV, R)                                                     \
  {                                                                         \
    float dot = qx*(RV).x + qy*(RV).y + qz*(RV).z;                          \
    float dd = (qq - 2.0f*dot) + (RV).w;                                    \
    bool c0 = dd < d0, c1 = dd < d1, c2 = dd < d2;                          \
    i2 = c1 ? i1 : (c2 ? (R) : i2);                                         \
    d2 = c1 ? d1 : fminf(d2, dd);                                           \
    i1 = c0 ? i0 : (c1 ? (R) : i1);                                         \
    d1 = c0 ? d0 : fminf(d1, dd);                                           \
    i0 = c0 ? (R) : i0;                                                     \
    d0 = fminf(d0, dd);                                                     \
  }

__launch_bounds__(256)
__global__ void k_fp2(const float* __restrict__ x, const float4* __restrict__ c1r4,
                      const float* __restrict__ g1,
                      const float* __restrict__ w1, const float* __restrict__ b1,
                      const float* __restrict__ w2, const float* __restrict__ b2,
                      const float* __restrict__ fcw, const float* __restrict__ fcb,
                      float* __restrict__ out) {
  __shared__ __align__(16) float sw1[67*32];
  __shared__ __align__(16) float sw2[32*32];
  __shared__ __align__(16) float sfc[64];
  __shared__ float sb1[32], sb2[32], sfcb[2];
  const int tid = threadIdx.x;
  const int b = blockIdx.x >> 7;
  const int n = ((blockIdx.x & 127) << 8) + tid;
  for (int i = tid; i < 67*32; i += 256) sw1[i] = w1[i];
  for (int i = tid; i < 32*32; i += 256) sw2[i] = w2[i];
  if (tid < 64) sfc[tid] = fcw[tid];
  if (tid < 32) { sb1[tid] = b1[tid]; sb2[tid] = b2[tid]; }
  if (tid < 2) sfcb[tid] = fcb[tid];
  __syncthreads();
  const float* xb = x + (size_t)b * N_ * 3;
  float qx = xb[3*n], qy = xb[3*n+1], qz = xb[3*n+2];
  float qq = qx*qx + qy*qy + qz*qz;
  const float4* refs = c1r4 + (size_t)b * S1_;
  float d0 = 3.402823466e+38f, d1 = d0, d2 = d0;
  int i0 = 0, i1 = 0, i2 = 0;
  for (int r = 0; r < S1_; r += 4) {
    float4 ra = refs[r+0];
    float4 rb = refs[r+1];
    float4 rc = refs[r+2];
    float4 rd = refs[r+3];
    FP2_PROC(ra, r+0);
    FP2_PROC(rb, r+1);
    FP2_PROC(rc, r+2);
    FP2_PROC(rd, r+3);
  }
  const float* g1b = g1 + (size_t)b * S1_ * 64;
  const float4* p0 = (const float4*)(g1b + (size_t)i0 * 64);
  const float4* p1 = (const float4*)(g1b + (size_t)i1 * 64);
  const float4* p2 = (const float4*)(g1b + (size_t)i2 * 64);
  const float THIRD = 1.0f / 3.0f;
  float h1r[32];
  #pragma unroll
  for (int k = 0; k < 32; ++k) h1r[k] = sb1[k];
  // rows 0..2: query coords
  #pragma unroll
  for (int i = 0; i < 3; ++i) {
    float v = (i == 0) ? qx : (i == 1) ? qy : qz;
    const float4* wrow = (const float4*)(sw1 + i*32);
    #pragma unroll
    for (int kq = 0; kq < 8; ++kq) {
      float4 wv = wrow[kq];
      h1r[4*kq+0] = fmaf(v, wv.x, h1r[4*kq+0]);
      h1r[4*kq+1] = fmaf(v, wv.y, h1r[4*kq+1]);
      h1r[4*kq+2] = fmaf(v, wv.z, h1r[4*kq+2]);
      h1r[4*kq+3] = fmaf(v, wv.w, h1r[4*kq+3]);
    }
  }
  // rows 3..66: interpolated features computed on the fly (no fi[64] array)
  #pragma unroll 4
  for (int o = 0; o < 16; ++o) {
    float4 a = p0[o], bq = p1[o], cq = p2[o];
    float vv[4];
    vv[0] = (a.x + bq.x + cq.x) * THIRD;
    vv[1] = (a.y + bq.y + cq.y) * THIRD;
    vv[2] = (a.z + bq.z + cq.z) * THIRD;
    vv[3] = (a.w + bq.w + cq.w) * THIRD;
    #pragma unroll
    for (int j = 0; j < 4; ++j) {
      float v = vv[j];
      const float4* wrow = (const float4*)(sw1 + (3 + 4*o + j)*32);
      #pragma unroll
      for (int kq = 0; kq < 8; ++kq) {
        float4 wv = wrow[kq];
        h1r[4*kq+0] = fmaf(v, wv.x, h1r[4*kq+0]);
        h1r[4*kq+1] = fmaf(v, wv.y, h1r[4*kq+1]);
        h1r[4*kq+2] = fmaf(v, wv.z, h1r[4*kq+2]);
        h1r[4*kq+3] = fmaf(v, wv.w, h1r[4*kq+3]);
      }
    }
  }
  #pragma unroll
  for (int k = 0; k < 32; ++k) h1r[k] = fmaxf(h1r[k], 0.0f);
  float h2r[32];
  #pragma unroll
  for (int m = 0; m < 32; ++m) h2r[m] = sb2[m];
  #pragma unroll
  for (int k = 0; k < 32; ++k) {
    float v = h1r[k];
    const float4* wrow = (const float4*)(sw2 + k*32);
    #pragma unroll
    for (int mq = 0; mq < 8; ++mq) {
      float4 wv = wrow[mq];
      h2r[4*mq+0] = fmaf(v, wv.x, h2r[4*mq+0]);
      h2r[4*mq+1] = fmaf(v, wv.y, h2r[4*mq+1]);
      h2r[4*mq+2] = fmaf(v, wv.z, h2r[4*mq+2]);
      h2r[4*mq+3] = fmaf(v, wv.w, h2r[4*mq+3]);
    }
  }
  float l0 = sfcb[0], l1 = sfcb[1];
  #pragma unroll
  for (int m = 0; m < 32; ++m) {
    l0 = fmaf(h2r[m], sfc[2*m+0], l0);
    l1 = fmaf(h2r[m], sfc[2*m+1], l1);
  }
  float mx = fmaxf(l0, l1);
  float s0 = l0 - mx, s1 = l1 - mx;
  float lg = logf(expf(s0) + expf(s1));
  float2 res; res.x = s0 - lg; res.y = s1 - lg;
  ((float2*)out)[(size_t)b * N_ + n] = res;
}

// ================= launch =================
extern "C" void kernel_launch(void* const* d_in, const int* in_sizes, int n_in,
                              void* d_out, int out_size, void* d_ws, size_t ws_size,
                              hipStream_t stream) {
  (void)in_sizes; (void)n_in; (void)out_size; (void)ws_size;
  const float* x     = (const float*)d_in[0];
  const float* sa1w1 = (const float*)d_in[1];
  const float* sa1b1 = (const float*)d_in[2];
  const float* sa1w2 = (const float*)d_in[3];
  const float* sa1b2 = (const float*)d_in[4];
  const float* sa2w1 = (const float*)d_in[5];
  const float* sa2b1 = (const float*)d_in[6];
  const float* sa2w2 = (const float*)d_in[7];
  const float* sa2b2 = (const float*)d_in[8];
  const float* fp1w1 = (const float*)d_in[9];
  const float* fp1b1 = (const float*)d_in[10];
  const float* fp1w2 = (const float*)d_in[11];
  const float* fp1b2 = (const float*)d_in[12];
  const float* fp2w1 = (const float*)d_in[13];
  const float* fp2b1 = (const float*)d_in[14];
  const float* fp2w2 = (const float*)d_in[15];
  const float* fp2b2 = (const float*)d_in[16];
  const float* fcw   = (const float*)d_in[17];
  const float* fcb   = (const float*)d_in[18];
  float* out = (float*)d_out;
  char* ws = (char*)d_ws;
  float4* xr4  = (float4*)(ws + OFF_XR4);
  float*  c1   = (float*)(ws + OFF_C1);
  float4* c1r4 = (float4*)(ws + OFF_C1R4);
  float*  c2   = (float*)(ws + OFF_C2);
  int*    nidx1= (int*)(ws + OFF_NIDX1);
  float*  f1   = (float*)(ws + OFF_F1);
  int*    nidx2= (int*)(ws + OFF_NIDX2);
  float*  f2   = (float*)(ws + OFF_F2);
  float*  g1   = (float*)(ws + OFF_G1);

  Samps smp;
  compute_samples(smp.s1, smp.s2);

  hipLaunchKernelGGL(k_prep,    dim3(B_*N_/256), dim3(256), 0, stream, x, xr4);
  hipLaunchKernelGGL(k_centers, dim3((B_*(S1_+S2_)+255)/256), dim3(256), 0, stream,
                     x, smp, c1, c1r4, c2);
  hipLaunchKernelGGL(k_knn,     dim3(B_*S1_/4), dim3(256), 0, stream, xr4, c1, nidx1, N_, 9);
  hipLaunchKernelGGL(k_sa1mlp,  dim3(B_*S1_/4), dim3(256), 0, stream,
                     x, nidx1, sa1w1, sa1b1, sa1w2, sa1b2, f1);
  hipLaunchKernelGGL(k_knn,     dim3(B_*S2_/4), dim3(256), 0, stream, c1r4, c2, nidx2, S1_, 7);
  hipLaunchKernelGGL(k_sa2mlp,  dim3(B_*S2_), dim3(256), 0, stream,
                     f1, nidx2, sa2w1, sa2b1, sa2w2, sa2b2, f2);
  hipLaunchKernelGGL(k_fp1,     dim3(B_*S1_/4), dim3(256), 0, stream,
                     c1, c2, f1, f2, fp1w1, fp1b1, fp1w2, fp1b2, g1);
  hipLaunchKernelGGL(k_fp2,     dim3(B_*N_/256), dim3(256), 0, stream,
                     x, c1r4, g1, fp2w1, fp2b1, fp2w2, fp2b2, fcw, fcb, out);
}

// Round 11
// 397.710 us; speedup vs baseline: 1.4506x; 1.0132x over previous
//
#include <hip/hip_runtime.h>
#include <stdint.h>

#define B_ 8
#define N_ 32768
#define S1_ 512
#define S2_ 128

// ---------------- workspace layout (bytes) ----------------
#define OFF_XR4   ((size_t)0)        // B*N float4 (xyz, rr)          4194304
#define OFF_C1    ((size_t)4194304)  // B*512*3 f32                     49152
#define OFF_C1R4  ((size_t)4243456)  // B*512 float4                    65536
#define OFF_C2    ((size_t)4308992)  // B*128*3 f32                     12288
#define OFF_NIDX1 ((size_t)4321280)  // B*512*32 i32                   524288
#define OFF_F1    ((size_t)4845568)  // B*512*64 f32                   524288
#define OFF_NIDX2 ((size_t)5369856)  // B*128*32 i32                   131072
#define OFF_F2    ((size_t)5500928)  // B*128*128 f32                  524288
#define OFF_G1    ((size_t)6025216)  // B*512*64 f32                   524288

struct Samps { int s1[S1_]; int s2[S2_]; };

// ================= host: replicate np.random.default_rng(0) =================
typedef unsigned __int128 u128;
struct RngState { u128 state, inc; bool has32; uint32_t saved; };

static uint64_t rng_next64(RngState* r) {
  const u128 MULT = ((u128)0x2360ed051fc65da4ULL << 64) | 0x4385df649fccf645ULL;
  r->state = r->state * MULT + r->inc;
  uint64_t hi = (uint64_t)(r->state >> 64), lo = (uint64_t)r->state;
  uint64_t xs = hi ^ lo;
  unsigned rot = (unsigned)(r->state >> 122);
  return (xs >> rot) | (xs << ((64u - rot) & 63u));
}
static uint32_t rng_next32(RngState* r) {
  if (r->has32) { r->has32 = false; return r->saved; }
  uint64_t v = rng_next64(r);
  r->has32 = true; r->saved = (uint32_t)(v >> 32);
  return (uint32_t)v;
}
static uint32_t rng_interval(RngState* r, uint32_t mx) {
  if (mx == 0) return 0;
  uint32_t mask = mx;
  mask |= mask >> 1; mask |= mask >> 2; mask |= mask >> 4;
  mask |= mask >> 8; mask |= mask >> 16;
  uint32_t v;
  while ((v = (rng_next32(r) & mask)) > mx) {}
  return v;
}
static void compute_samples(int* s1, int* s2) {
  uint32_t pool[4];
  uint32_t hc = 0x43b0d7e5u;
  auto hmix = [&hc](uint32_t v) -> uint32_t {
    v ^= hc; hc *= 0x931e8875u; v *= hc; v ^= v >> 16; return v;
  };
  auto mixf = [](uint32_t x, uint32_t y) -> uint32_t {
    uint32_t rr = (x * 0xca01f9ddu) ^ (y * 0x4973f715u);
    rr ^= rr >> 16; return rr;
  };
  pool[0] = hmix(0u); pool[1] = hmix(0u); pool[2] = hmix(0u); pool[3] = hmix(0u);
  for (int s = 0; s < 4; ++s)
    for (int d = 0; d < 4; ++d)
      if (s != d) pool[d] = mixf(pool[d], hmix(pool[s]));
  uint32_t hc2 = 0x8b51f9ddu;
  uint32_t w32[8];
  for (int i = 0; i < 8; ++i) {
    uint32_t dv = pool[i & 3];
    dv ^= hc2; hc2 *= 0x58f38dedu; dv *= hc2; dv ^= dv >> 16;
    w32[i] = dv;
  }
  uint64_t w64[4];
  for (int i = 0; i < 4; ++i) w64[i] = (uint64_t)w32[2*i] | ((uint64_t)w32[2*i+1] << 32);
  const u128 MULT = ((u128)0x2360ed051fc65da4ULL << 64) | 0x4385df649fccf645ULL;
  u128 initstate = ((u128)w64[0] << 64) | w64[1];
  u128 initseq   = ((u128)w64[2] << 64) | w64[3];
  RngState r; r.has32 = false; r.saved = 0;
  r.inc = (initseq << 1) | 1;
  r.state = 0;
  r.state = r.state * MULT + r.inc;
  r.state += initstate;
  r.state = r.state * MULT + r.inc;
  static int perm1[N_];
  for (int i = 0; i < N_; ++i) perm1[i] = i;
  for (int i = N_ - 1; i > 0; --i) {
    uint32_t j = rng_interval(&r, (uint32_t)i);
    int t = perm1[i]; perm1[i] = perm1[j]; perm1[j] = t;
  }
  for (int i = 0; i < S1_; ++i) s1[i] = perm1[i];
  int perm2[S1_];
  for (int i = 0; i < S1_; ++i) perm2[i] = i;
  for (int i = S1_ - 1; i > 0; --i) {
    uint32_t j = rng_interval(&r, (uint32_t)i);
    int t = perm2[i]; perm2[i] = perm2[j]; perm2[j] = t;
  }
  for (int i = 0; i < S2_; ++i) s2[i] = perm2[i];
}

// ================= device =================

__global__ void k_prep(const float* __restrict__ x, float4* __restrict__ xr4) {
  int t = blockIdx.x * blockDim.x + threadIdx.x;
  float a = x[3*t], b = x[3*t+1], c = x[3*t+2];
  xr4[t] = make_float4(a, b, c, a*a + b*b + c*c);
}

__global__ void k_centers(const float* __restrict__ x, Samps sm,
                          float* __restrict__ c1, float4* __restrict__ c1r4,
                          float* __restrict__ c2) {
  int t = blockIdx.x * blockDim.x + threadIdx.x;
  if (t < B_*S1_) {
    int b = t >> 9, c = t & (S1_-1);
    int sidx = sm.s1[c];
    const float* src = x + ((size_t)b*N_ + sidx)*3;
    float a = src[0], bb = src[1], cc = src[2];
    c1[(size_t)t*3+0] = a; c1[(size_t)t*3+1] = bb; c1[(size_t)t*3+2] = cc;
    c1r4[t] = make_float4(a, bb, cc, a*a + bb*bb + cc*cc);
  } else {
    int u = t - B_*S1_;
    if (u < B_*S2_) {
      int b = u >> 7, c = u & (S2_-1);
      int sidx = sm.s1[sm.s2[c]];
      const float* src = x + ((size_t)b*N_ + sidx)*3;
      c2[(size_t)u*3+0] = src[0]; c2[(size_t)u*3+1] = src[1]; c2[(size_t)u*3+2] = src[2];
    }
  }
}

// ---- kNN: 2 waves per query (128-thr block), each wave scans half the refs.
//      Per-wave: bitonic prologue (u64 keys) -> float-domain sorted-insert list
//      with float threshold prefilter. Exact (dist,idx) tie-break preserved:
//      ascending-index scan => equal-dist incoming lands at pos>=its equals;
//      ties at the 32nd slot land at pos>=32 (no-op on top-32). Cross-wave
//      merge compares full u64 (twiddled-dist | idx) keys -> exact global. ----
#define KNN_KEY(RV, UB)                                                     \
  {                                                                         \
    float dot = qx*(RV).x + qy*(RV).y + qz*(RV).z;                          \
    float dd = (qq - 2.0f*dot) + (RV).w;                                    \
    (UB) = __float_as_uint(dd);                                             \
    (UB) ^= ((unsigned int)((int)(UB) >> 31)) | 0x80000000u;                \
  }

#define KNN_DIST(RV, DD)                                                    \
  {                                                                         \
    float dot = qx*(RV).x + qy*(RV).y + qz*(RV).z;                          \
    (DD) = (qq - 2.0f*dot) + (RV).w;                                        \
  }

#define KNN_INS_F(DD, PBASE)                                                \
  {                                                                         \
    bool cand = ((DD) <= Tf);                                               \
    while (__any(cand)) {                                                   \
      unsigned long long bal = __ballot(cand);                              \
      int src = (int)__builtin_ctzll(bal);                                  \
      float df = __shfl((DD), src);                                         \
      int ii = (PBASE) + src;                                               \
      int pos = __popcll(__ballot(ldf <= df));                              \
      float ud = __shfl_up(ldf, 1);                                         \
      int ui = __shfl_up(li, 1);                                            \
      if (lane == pos)      { ldf = df; li = ii; }                          \
      else if (lane > pos)  { ldf = ud; li = ui;  }                         \
      Tf = __shfl(ldf, 31);                                                 \
      cand = cand && ((DD) <= Tf) && (lane != src);                         \
    }                                                                       \
  }

__launch_bounds__(128)
__global__ void k_knn2(const float4* __restrict__ refs4, const float* __restrict__ qpts,
                       int* __restrict__ out_idx, int nrefs, int qshift) {
  __shared__ unsigned long long kbuf[64];
  const int tid = threadIdx.x, lane = tid & 63, wv = tid >> 6;
  const int q = blockIdx.x;
  const int b = q >> qshift;
  const float4* refs = refs4 + (size_t)b * nrefs;
  const int half = nrefs >> 1;
  const int base = wv * half;
  float qx = qpts[(size_t)q*3+0], qy = qpts[(size_t)q*3+1], qz = qpts[(size_t)q*3+2];
  float qq = qx*qx + qy*qy + qz*qz;
  float ldf, Tf;
  int li;
  {
    // prologue: first 64 refs of this slice via one u64 bitonic sort (exact (dist,idx))
    float4 rv = refs[base + lane];
    unsigned int ub; KNN_KEY(rv, ub);
    unsigned long long key = ((unsigned long long)ub << 32) | (unsigned int)(base + lane);
    #pragma unroll
    for (int k2 = 2; k2 <= 64; k2 <<= 1) {
      #pragma unroll
      for (int j = k2 >> 1; j >= 1; j >>= 1) {
        unsigned long long o = __shfl_xor(key, j);
        bool keepmin = (((lane & j) == 0) == ((lane & k2) == 0));
        if ((o < key) == keepmin) key = o;
      }
    }
    unsigned int td = (unsigned int)(key >> 32);
    li = (int)(key & 0xffffffffu);
    // untwiddle order-map: top bit set -> b = u ^ 0x80000000 ; else b = ~u
    int tt = (int)td >> 31;
    unsigned int mask = tt ? 0x80000000u : 0xFFFFFFFFu;
    ldf = __uint_as_float(td ^ mask);
    Tf = __shfl(ldf, 31);
  }
  {
    // rest of the first 256 of this slice (refs base+64 .. base+255)
    float4 r1 = refs[base + 64 + lane];
    float4 r2 = refs[base + 128 + lane];
    float4 r3 = refs[base + 192 + lane];
    float dd1, dd2, dd3;
    KNN_DIST(r1, dd1); KNN_DIST(r2, dd2); KNN_DIST(r3, dd3);
    KNN_INS_F(dd1, base + 64);
    KNN_INS_F(dd2, base + 128);
    KNN_INS_F(dd3, base + 192);
  }
  for (int g = base + 256; g + 255 < base + half; g += 256) {
    float4 r0 = refs[g + lane];
    float4 r1 = refs[g + 64 + lane];
    float4 r2 = refs[g + 128 + lane];
    float4 r3 = refs[g + 192 + lane];
    float dd0, dd1, dd2, dd3;
    KNN_DIST(r0, dd0); KNN_DIST(r1, dd1); KNN_DIST(r2, dd2); KNN_DIST(r3, dd3);
    KNN_INS_F(dd0, g);
    KNN_INS_F(dd1, g + 64);
    KNN_INS_F(dd2, g + 128);
    KNN_INS_F(dd3, g + 192);
  }
  // pack top-32 of this wave as u64 keys (re-twiddle float for order-preserving bits)
  {
    unsigned int ub2 = __float_as_uint(ldf);
    ub2 ^= ((unsigned int)((int)ub2 >> 31)) | 0x80000000u;
    unsigned long long key = ((unsigned long long)ub2 << 32) | (unsigned int)li;
    if (lane < 32) kbuf[wv * 32 + lane] = key;
  }
  __syncthreads();
  if (wv == 0) {
    // lanes 0-31: wave0 list ascending; lanes 32-63: wave1 list reversed (descending)
    int srcl = (lane < 32) ? lane : (95 - lane);
    unsigned long long v = kbuf[srcl];
    #pragma unroll
    for (int j = 32; j >= 1; j >>= 1) {
      unsigned long long o = __shfl_xor(v, j);
      bool keepmin = ((lane & j) == 0);
      if ((o < v) == keepmin) v = o;
    }
    if (lane < 32) out_idx[(size_t)q*32 + lane] = (int)(v & 0xffffffffu);
  }
}

// ---- SA1 MLP (3->64 relu ->64) + max over 32 neighbors; wave per center.
//      Wave-private LDS broadcast => NO barriers; pipelined neighbor gather. ----
__launch_bounds__(256)
__global__ void k_sa1mlp(const float* __restrict__ x, const int* __restrict__ nidx1,
                         const float* __restrict__ w1, const float* __restrict__ b1,
                         const float* __restrict__ w2, const float* __restrict__ b2,
                         float* __restrict__ f1) {
  __shared__ __align__(16) float hbuf[4][64];
  const int tid = threadIdx.x, wave = tid >> 6, lane = tid & 63;
  const int q = blockIdx.x * 4 + wave;
  const int b = q >> 9;
  const float* xb = x + (size_t)b * N_ * 3;
  float wc0 = w1[lane], wc1 = w1[64 + lane], wc2 = w1[128 + lane];
  float b1v = b1[lane], b2v = b2[lane];
  float w2c[64];
  #pragma unroll
  for (int h = 0; h < 64; ++h) w2c[h] = w2[h*64 + lane];
  const int* nb = nidx1 + (size_t)q * 32;
  int n0 = nb[0];
  float px = xb[3*n0], py = xb[3*n0+1], pz = xb[3*n0+2];
  float fm = -3.402823466e+38f;
  for (int j = 0; j < 32; ++j) {
    int n2 = nb[(j + 1) & 31];
    float nx = xb[3*n2], ny = xb[3*n2+1], nz = xb[3*n2+2];
    float h1 = fmaf(px, wc0, fmaf(py, wc1, fmaf(pz, wc2, b1v)));
    h1 = fmaxf(h1, 0.0f);
    hbuf[wave][lane] = h1;                    // wave-private: no barrier needed
    float acc = b2v;
    const float4* hv = (const float4*)(&hbuf[wave][0]);
    #pragma unroll
    for (int h4 = 0; h4 < 16; ++h4) {
      float4 v = hv[h4];
      acc = fmaf(v.x, w2c[4*h4+0], acc);
      acc = fmaf(v.y, w2c[4*h4+1], acc);
      acc = fmaf(v.z, w2c[4*h4+2], acc);
      acc = fmaf(v.w, w2c[4*h4+3], acc);
    }
    fm = fmaxf(fm, acc);
    px = nx; py = ny; pz = nz;
  }
  f1[(size_t)q*64 + lane] = fm;
}

// ---- SA2 MLP (64->128 relu ->128) + max; block(256) per center, split-K over s ----
__launch_bounds__(256)
__global__ void k_sa2mlp(const float* __restrict__ f1, const int* __restrict__ nidx2,
                         const float* __restrict__ w1, const float* __restrict__ b1,
                         const float* __restrict__ w2, const float* __restrict__ b2,
                         float* __restrict__ f2) {
  __shared__ __align__(16) float fin[64];
  __shared__ __align__(16) float h1s[128];
  __shared__ float ph[128];
  const int tid = threadIdx.x;
  const int s = tid >> 7, t = tid & 127;
  const int q = blockIdx.x;
  const int b = q >> 7;
  float w1r[32], w2r[64];
  #pragma unroll
  for (int i = 0; i < 32; ++i) w1r[i] = w1[(s*32 + i)*128 + t];
  #pragma unroll
  for (int h = 0; h < 64; ++h) w2r[h] = w2[(s*64 + h)*128 + t];
  float b1v = b1[t], b2v = b2[t];
  const int* nb = nidx2 + (size_t)q * 32;
  float fm = -3.402823466e+38f;
  for (int j = 0; j < 32; ++j) {
    int n = nb[j];
    __syncthreads();
    if (tid < 64) fin[tid] = f1[((size_t)b * S1_ + n)*64 + tid];
    __syncthreads();
    float p1 = 0.0f;
    const float4* fv = (const float4*)(fin + s*32);
    #pragma unroll
    for (int i4 = 0; i4 < 8; ++i4) {
      float4 v = fv[i4];
      p1 = fmaf(v.x, w1r[4*i4+0], p1);
      p1 = fmaf(v.y, w1r[4*i4+1], p1);
      p1 = fmaf(v.z, w1r[4*i4+2], p1);
      p1 = fmaf(v.w, w1r[4*i4+3], p1);
    }
    if (s) ph[t] = p1;
    __syncthreads();
    if (!s) h1s[t] = fmaxf(p1 + ph[t] + b1v, 0.0f);
    __syncthreads();
    float p2 = 0.0f;
    const float4* hv = (const float4*)(h1s + s*64);
    #pragma unroll
    for (int h4 = 0; h4 < 16; ++h4) {
      float4 v = hv[h4];
      p2 = fmaf(v.x, w2r[4*h4+0], p2);
      p2 = fmaf(v.y, w2r[4*h4+1], p2);
      p2 = fmaf(v.z, w2r[4*h4+2], p2);
      p2 = fmaf(v.w, w2r[4*h4+3], p2);
    }
    if (s) ph[t] = p2;
    __syncthreads();
    if (!s) fm = fmaxf(fm, p2 + ph[t] + b2v);
  }
  if (!s) f2[(size_t)q*128 + t] = fm;
}

// ---- FP1: kNN-3 over 128 refs + interp + MLP(192->64 relu ->64); wave per query ----
__launch_bounds__(256)
__global__ void k_fp1(const float* __restrict__ c1, const float* __restrict__ c2,
                      const float* __restrict__ f1, const float* __restrict__ f2,
                      const float* __restrict__ w1, const float* __restrict__ b1,
                      const float* __restrict__ w2, const float* __restrict__ b2,
                      float* __restrict__ g1) {
  __shared__ __align__(16) float sw1[192*64];
  __shared__ __align__(16) float sw2[64*64];
  __shared__ __align__(16) float sinp[4][192];
  __shared__ __align__(16) float sh1[4][64];
  __shared__ __align__(16) float4 srefs4[S2_];
  const int tid = threadIdx.x;
  const int wave = tid >> 6, lane = tid & 63;
  const int q = blockIdx.x * 4 + wave;
  const int b = q >> 9;
  for (int i = tid; i < 192*64; i += 256) sw1[i] = w1[i];
  for (int i = tid; i < 64*64; i += 256) sw2[i] = w2[i];
  if (tid < S2_) {
    const float* rp = c2 + ((size_t)b * S2_ + tid) * 3;
    float rx = rp[0], ry = rp[1], rz = rp[2];
    srefs4[tid] = make_float4(rx, ry, rz, rx*rx + ry*ry + rz*rz);
  }
  __syncthreads();
  float qx = c1[(size_t)q*3+0], qy = c1[(size_t)q*3+1], qz = c1[(size_t)q*3+2];
  float qq = qx*qx + qy*qy + qz*qz;
  unsigned long long ka, kb;
  {
    float4 rv = srefs4[lane];
    float dot = qx*rv.x + qy*rv.y + qz*rv.z;
    float d = (qq - 2.0f*dot) + rv.w;
    unsigned int ub = __float_as_uint(d);
    ub ^= ((unsigned int)((int)ub >> 31)) | 0x80000000u;
    ka = ((unsigned long long)ub << 32) | (unsigned int)lane;
    rv = srefs4[lane + 64];
    dot = qx*rv.x + qy*rv.y + qz*rv.z;
    d = (qq - 2.0f*dot) + rv.w;
    ub = __float_as_uint(d);
    ub ^= ((unsigned int)((int)ub >> 31)) | 0x80000000u;
    kb = ((unsigned long long)ub << 32) | (unsigned int)(lane + 64);
    if (kb < ka) { unsigned long long tt = ka; ka = kb; kb = tt; }
  }
  int nsel[3];
  #pragma unroll
  for (int r = 0; r < 3; ++r) {
    unsigned long long m = ka;
    #pragma unroll
    for (int s = 1; s < 64; s <<= 1) {
      unsigned long long o = __shfl_xor(m, s);
      if (o < m) m = o;
    }
    nsel[r] = (int)(m & 0xffffffffu);
    if (ka == m) { ka = kb; kb = ~0ULL; }
  }
  const float* f2b = f2 + (size_t)b * S2_ * 128;
  sinp[wave][lane] = f1[(size_t)q*64 + lane];
  {
    float a0 = f2b[(size_t)nsel[0]*128 + lane];
    float a1 = f2b[(size_t)nsel[1]*128 + lane];
    float a2 = f2b[(size_t)nsel[2]*128 + lane];
    sinp[wave][64 + lane] = (a0 + a1 + a2) / 3.0f;
    a0 = f2b[(size_t)nsel[0]*128 + 64 + lane];
    a1 = f2b[(size_t)nsel[1]*128 + 64 + lane];
    a2 = f2b[(size_t)nsel[2]*128 + 64 + lane];
    sinp[wave][128 + lane] = (a0 + a1 + a2) / 3.0f;
  }
  __syncthreads();
  float acc = b1[lane];
  const float4* sv = (const float4*)(&sinp[wave][0]);
  #pragma unroll
  for (int i4 = 0; i4 < 48; ++i4) {
    float4 v = sv[i4];
    acc = fmaf(v.x, sw1[(4*i4+0)*64 + lane], acc);
    acc = fmaf(v.y, sw1[(4*i4+1)*64 + lane], acc);
    acc = fmaf(v.z, sw1[(4*i4+2)*64 + lane], acc);
    acc = fmaf(v.w, sw1[(4*i4+3)*64 + lane], acc);
  }
  sh1[wave][lane] = fmaxf(acc, 0.0f);
  __syncthreads();
  float acc2 = b2[lane];
  const float4* hv = (const float4*)(&sh1[wave][0]);
  #pragma unroll
  for (int h4 = 0; h4 < 16; ++h4) {
    float4 v = hv[h4];
    acc2 = fmaf(v.x, sw2[(4*h4+0)*64 + lane], acc2);
    acc2 = fmaf(v.y, sw2[(4*h4+1)*64 + lane], acc2);
    acc2 = fmaf(v.z, sw2[(4*h4+2)*64 + lane], acc2);
    acc2 = fmaf(v.w, sw2[(4*h4+3)*64 + lane], acc2);
  }
  g1[(size_t)q*64 + lane] = acc2;
}

// ---- FP2: kNN-3 over 512 refs + interp + MLP(67->32 relu ->32) + FC + log_softmax ----
// Scan streams refs from GLOBAL c1r4 (wave-uniform addr, L1-resident); interp
// folded into w1 loop (no fi[64]); *(1/3) instead of fdiv.
#define FP2_PROC(RV, R)                                                     \
  {                                                                         \
    float dot = qx*(RV).x + qy*(RV).y + qz*(RV).z;                          \
    float dd = (qq - 2.0f*dot) + (RV).w;                                    \
    bool c0 = dd < d0, c1 = dd < d1, c2 = dd < d2;                          \
    i2 = c1 ? i1 : (c2 ? (R) : i2);                                         \
    d2 = c1 ? d1 : fminf(d2, dd);                                           \
    i1 = c0 ? i0 : (c1 ? (R) : i1);                                         \
    d1 = c0 ? d0 : fminf(d1, dd);                                           \
    i0 = c0 ? (R) : i0;                                                     \
    d0 = fminf(d0, dd);                                                     \
  }

__launch_bounds__(256)
__global__ void k_fp2(const float* __restrict__ x, const float4* __restrict__ c1r4,
                      const float* __restrict__ g1,
                      const float* __restrict__ w1, const float* __restrict__ b1,
                      const float* __restrict__ w2, const float* __restrict__ b2,
                      const float* __restrict__ fcw, const float* __restrict__ fcb,
                      float* __restrict__ out) {
  __shared__ __align__(16) float sw1[67*32];
  __shared__ __align__(16) float sw2[32*32];
  __shared__ __align__(16) float sfc[64];
  __shared__ float sb1[32], sb2[32], sfcb[2];
  const int tid = threadIdx.x;
  const int b = blockIdx.x >> 7;
  const int n = ((blockIdx.x & 127) << 8) + tid;
  for (int i = tid; i < 67*32; i += 256) sw1[i] = w1[i];
  for (int i = tid; i < 32*32; i += 256) sw2[i] = w2[i];
  if (tid < 64) sfc[tid] = fcw[tid];
  if (tid < 32) { sb1[tid] = b1[tid]; sb2[tid] = b2[tid]; }
  if (tid < 2) sfcb[tid] = fcb[tid];
  __syncthreads();
  const float* xb = x + (size_t)b * N_ * 3;
  float qx = xb[3*n], qy = xb[3*n+1], qz = xb[3*n+2];
  float qq = qx*qx + qy*qy + qz*qz;
  const float4* refs = c1r4 + (size_t)b * S1_;
  float d0 = 3.402823466e+38f, d1 = d0, d2 = d0;
  int i0 = 0, i1 = 0, i2 = 0;
  for (int r = 0; r < S1_; r += 4) {
    float4 ra = refs[r+0];
    float4 rb = refs[r+1];
    float4 rc = refs[r+2];
    float4 rd = refs[r+3];
    FP2_PROC(ra, r+0);
    FP2_PROC(rb, r+1);
    FP2_PROC(rc, r+2);
    FP2_PROC(rd, r+3);
  }
  const float* g1b = g1 + (size_t)b * S1_ * 64;
  const float4* p0 = (const float4*)(g1b + (size_t)i0 * 64);
  const float4* p1 = (const float4*)(g1b + (size_t)i1 * 64);
  const float4* p2 = (const float4*)(g1b + (size_t)i2 * 64);
  const float THIRD = 1.0f / 3.0f;
  float h1r[32];
  #pragma unroll
  for (int k = 0; k < 32; ++k) h1r[k] = sb1[k];
  // rows 0..2: query coords
  #pragma unroll
  for (int i = 0; i < 3; ++i) {
    float v = (i == 0) ? qx : (i == 1) ? qy : qz;
    const float4* wrow = (const float4*)(sw1 + i*32);
    #pragma unroll
    for (int kq = 0; kq < 8; ++kq) {
      float4 wv = wrow[kq];
      h1r[4*kq+0] = fmaf(v, wv.x, h1r[4*kq+0]);
      h1r[4*kq+1] = fmaf(v, wv.y, h1r[4*kq+1]);
      h1r[4*kq+2] = fmaf(v, wv.z, h1r[4*kq+2]);
      h1r[4*kq+3] = fmaf(v, wv.w, h1r[4*kq+3]);
    }
  }
  // rows 3..66: interpolated features computed on the fly (no fi[64] array)
  #pragma unroll 4
  for (int o = 0; o < 16; ++o) {
    float4 a = p0[o], bq = p1[o], cq = p2[o];
    float vv[4];
    vv[0] = (a.x + bq.x + cq.x) * THIRD;
    vv[1] = (a.y + bq.y + cq.y) * THIRD;
    vv[2] = (a.z + bq.z + cq.z) * THIRD;
    vv[3] = (a.w + bq.w + cq.w) * THIRD;
    #pragma unroll
    for (int j = 0; j < 4; ++j) {
      float v = vv[j];
      const float4* wrow = (const float4*)(sw1 + (3 + 4*o + j)*32);
      #pragma unroll
      for (int kq = 0; kq < 8; ++kq) {
        float4 wv = wrow[kq];
        h1r[4*kq+0] = fmaf(v, wv.x, h1r[4*kq+0]);
        h1r[4*kq+1] = fmaf(v, wv.y, h1r[4*kq+1]);
        h1r[4*kq+2] = fmaf(v, wv.z, h1r[4*kq+2]);
        h1r[4*kq+3] = fmaf(v, wv.w, h1r[4*kq+3]);
      }
    }
  }
  #pragma unroll
  for (int k = 0; k < 32; ++k) h1r[k] = fmaxf(h1r[k], 0.0f);
  float h2r[32];
  #pragma unroll
  for (int m = 0; m < 32; ++m) h2r[m] = sb2[m];
  #pragma unroll
  for (int k = 0; k < 32; ++k) {
    float v = h1r[k];
    const float4* wrow = (const float4*)(sw2 + k*32);
    #pragma unroll
    for (int mq = 0; mq < 8; ++mq) {
      float4 wv = wrow[mq];
      h2r[4*mq+0] = fmaf(v, wv.x, h2r[4*mq+0]);
      h2r[4*mq+1] = fmaf(v, wv.y, h2r[4*mq+1]);
      h2r[4*mq+2] = fmaf(v, wv.z, h2r[4*mq+2]);
      h2r[4*mq+3] = fmaf(v, wv.w, h2r[4*mq+3]);
    }
  }
  float l0 = sfcb[0], l1 = sfcb[1];
  #pragma unroll
  for (int m = 0; m < 32; ++m) {
    l0 = fmaf(h2r[m], sfc[2*m+0], l0);
    l1 = fmaf(h2r[m], sfc[2*m+1], l1);
  }
  float mx = fmaxf(l0, l1);
  float s0 = l0 - mx, s1 = l1 - mx;
  float lg = logf(expf(s0) + expf(s1));
  float2 res; res.x = s0 - lg; res.y = s1 - lg;
  ((float2*)out)[(size_t)b * N_ + n] = res;
}

// ================= launch =================
extern "C" void kernel_launch(void* const* d_in, const int* in_sizes, int n_in,
                              void* d_out, int out_size, void* d_ws, size_t ws_size,
                              hipStream_t stream) {
  (void)in_sizes; (void)n_in; (void)out_size; (void)ws_size;
  const float* x     = (const float*)d_in[0];
  const float* sa1w1 = (const float*)d_in[1];
  const float* sa1b1 = (const float*)d_in[2];
  const float* sa1w2 = (const float*)d_in[3];
  const float* sa1b2 = (const float*)d_in[4];
  const float* sa2w1 = (const float*)d_in[5];
  const float* sa2b1 = (const float*)d_in[6];
  const float* sa2w2 = (const float*)d_in[7];
  const float* sa2b2 = (const float*)d_in[8];
  const float* fp1w1 = (const float*)d_in[9];
  const float* fp1b1 = (const float*)d_in[10];
  const float* fp1w2 = (const float*)d_in[11];
  const float* fp1b2 = (const float*)d_in[12];
  const float* fp2w1 = (const float*)d_in[13];
  const float* fp2b1 = (const float*)d_in[14];
  const float* fp2w2 = (const float*)d_in[15];
  const float* fp2b2 = (const float*)d_in[16];
  const float* fcw   = (const float*)d_in[17];
  const float* fcb   = (const float*)d_in[18];
  float* out = (float*)d_out;
  char* ws = (char*)d_ws;
  float4* xr4  = (float4*)(ws + OFF_XR4);
  float*  c1   = (float*)(ws + OFF_C1);
  float4* c1r4 = (float4*)(ws + OFF_C1R4);
  float*  c2   = (float*)(ws + OFF_C2);
  int*    nidx1= (int*)(ws + OFF_NIDX1);
  float*  f1   = (float*)(ws + OFF_F1);
  int*    nidx2= (int*)(ws + OFF_NIDX2);
  float*  f2   = (float*)(ws + OFF_F2);
  float*  g1   = (float*)(ws + OFF_G1);

  Samps smp;
  compute_samples(smp.s1, smp.s2);

  hipLaunchKernelGGL(k_prep,    dim3(B_*N_/256), dim3(256), 0, stream, x, xr4);
  hipLaunchKernelGGL(k_centers, dim3((B_*(S1_+S2_)+255)/256), dim3(256), 0, stream,
                     x, smp, c1, c1r4, c2);
  hipLaunchKernelGGL(k_knn2,    dim3(B_*S1_), dim3(128), 0, stream, xr4, c1, nidx1, N_, 9);
  hipLaunchKernelGGL(k_sa1mlp,  dim3(B_*S1_/4), dim3(256), 0, stream,
                     x, nidx1, sa1w1, sa1b1, sa1w2, sa1b2, f1);
  hipLaunchKernelGGL(k_knn2,    dim3(B_*S2_), dim3(128), 0, stream, c1r4, c2, nidx2, S1_, 7);
  hipLaunchKernelGGL(k_sa2mlp,  dim3(B_*S2_), dim3(256), 0, stream,
                     f1, nidx2, sa2w1, sa2b1, sa2w2, sa2b2, f2);
  hipLaunchKernelGGL(k_fp1,     dim3(B_*S1_/4), dim3(256), 0, stream,
                     c1, c2, f1, f2, fp1w1, fp1b1, fp1w2, fp1b2, g1);
  hipLaunchKernelGGL(k_fp2,     dim3(B_*N_/256), dim3(256), 0, stream,
                     x, c1r4, g1, fp2w1, fp2b1, fp2w2, fp2b2, fcw, fcb, out);
}

// Round 13
// 375.284 us; speedup vs baseline: 1.5372x; 1.0598x over previous
//
#include <hip/hip_runtime.h>
#include <stdint.h>

#define B_ 8
#define N_ 32768
#define S1_ 512
#define S2_ 128

// ---------------- workspace layout (bytes) ----------------
#define OFF_XR4   ((size_t)0)        // B*N float4 (xyz, rr)          4194304
#define OFF_C1    ((size_t)4194304)  // B*512*3 f32                     49152
#define OFF_C1R4  ((size_t)4243456)  // B*512 float4                    65536
#define OFF_C2    ((size_t)4308992)  // B*128*3 f32                     12288
#define OFF_NIDX1 ((size_t)4321280)  // B*512*32 i32                   524288
#define OFF_F1    ((size_t)4845568)  // B*512*64 f32                   524288
#define OFF_NIDX2 ((size_t)5369856)  // B*128*32 i32                   131072
#define OFF_F2    ((size_t)5500928)  // B*128*128 f32                  524288
#define OFF_G1    ((size_t)6025216)  // B*512*64 f32                   524288

struct Samps { int s1[S1_]; int s2[S2_]; };

// ================= host: replicate np.random.default_rng(0) =================
typedef unsigned __int128 u128;
struct RngState { u128 state, inc; bool has32; uint32_t saved; };

static uint64_t rng_next64(RngState* r) {
  const u128 MULT = ((u128)0x2360ed051fc65da4ULL << 64) | 0x4385df649fccf645ULL;
  r->state = r->state * MULT + r->inc;
  uint64_t hi = (uint64_t)(r->state >> 64), lo = (uint64_t)r->state;
  uint64_t xs = hi ^ lo;
  unsigned rot = (unsigned)(r->state >> 122);
  return (xs >> rot) | (xs << ((64u - rot) & 63u));
}
static uint32_t rng_next32(RngState* r) {
  if (r->has32) { r->has32 = false; return r->saved; }
  uint64_t v = rng_next64(r);
  r->has32 = true; r->saved = (uint32_t)(v >> 32);
  return (uint32_t)v;
}
static uint32_t rng_interval(RngState* r, uint32_t mx) {
  if (mx == 0) return 0;
  uint32_t mask = mx;
  mask |= mask >> 1; mask |= mask >> 2; mask |= mask >> 4;
  mask |= mask >> 8; mask |= mask >> 16;
  uint32_t v;
  while ((v = (rng_next32(r) & mask)) > mx) {}
  return v;
}
static void compute_samples(int* s1, int* s2) {
  uint32_t pool[4];
  uint32_t hc = 0x43b0d7e5u;
  auto hmix = [&hc](uint32_t v) -> uint32_t {
    v ^= hc; hc *= 0x931e8875u; v *= hc; v ^= v >> 16; return v;
  };
  auto mixf = [](uint32_t x, uint32_t y) -> uint32_t {
    uint32_t rr = (x * 0xca01f9ddu) ^ (y * 0x4973f715u);
    rr ^= rr >> 16; return rr;
  };
  pool[0] = hmix(0u); pool[1] = hmix(0u); pool[2] = hmix(0u); pool[3] = hmix(0u);
  for (int s = 0; s < 4; ++s)
    for (int d = 0; d < 4; ++d)
      if (s != d) pool[d] = mixf(pool[d], hmix(pool[s]));
  uint32_t hc2 = 0x8b51f9ddu;
  uint32_t w32[8];
  for (int i = 0; i < 8; ++i) {
    uint32_t dv = pool[i & 3];
    dv ^= hc2; hc2 *= 0x58f38dedu; dv *= hc2; dv ^= dv >> 16;
    w32[i] = dv;
  }
  uint64_t w64[4];
  for (int i = 0; i < 4; ++i) w64[i] = (uint64_t)w32[2*i] | ((uint64_t)w32[2*i+1] << 32);
  const u128 MULT = ((u128)0x2360ed051fc65da4ULL << 64) | 0x4385df649fccf645ULL;
  u128 initstate = ((u128)w64[0] << 64) | w64[1];
  u128 initseq   = ((u128)w64[2] << 64) | w64[3];
  RngState r; r.has32 = false; r.saved = 0;
  r.inc = (initseq << 1) | 1;
  r.state = 0;
  r.state = r.state * MULT + r.inc;
  r.state += initstate;
  r.state = r.state * MULT + r.inc;
  static int perm1[N_];
  for (int i = 0; i < N_; ++i) perm1[i] = i;
  for (int i = N_ - 1; i > 0; --i) {
    uint32_t j = rng_interval(&r, (uint32_t)i);
    int t = perm1[i]; perm1[i] = perm1[j]; perm1[j] = t;
  }
  for (int i = 0; i < S1_; ++i) s1[i] = perm1[i];
  int perm2[S1_];
  for (int i = 0; i < S1_; ++i) perm2[i] = i;
  for (int i = S1_ - 1; i > 0; --i) {
    uint32_t j = rng_interval(&r, (uint32_t)i);
    int t = perm2[i]; perm2[i] = perm2[j]; perm2[j] = t;
  }
  for (int i = 0; i < S2_; ++i) s2[i] = perm2[i];
}

// ================= device =================

__global__ void k_prep(const float* __restrict__ x, float4* __restrict__ xr4) {
  int t = blockIdx.x * blockDim.x + threadIdx.x;
  float a = x[3*t], b = x[3*t+1], c = x[3*t+2];
  xr4[t] = make_float4(a, b, c, a*a + b*b + c*c);
}

__global__ void k_centers(const float* __restrict__ x, Samps sm,
                          float* __restrict__ c1, float4* __restrict__ c1r4,
                          float* __restrict__ c2) {
  int t = blockIdx.x * blockDim.x + threadIdx.x;
  if (t < B_*S1_) {
    int b = t >> 9, c = t & (S1_-1);
    int sidx = sm.s1[c];
    const float* src = x + ((size_t)b*N_ + sidx)*3;
    float a = src[0], bb = src[1], cc = src[2];
    c1[(size_t)t*3+0] = a; c1[(size_t)t*3+1] = bb; c1[(size_t)t*3+2] = cc;
    c1r4[t] = make_float4(a, bb, cc, a*a + bb*bb + cc*cc);
  } else {
    int u = t - B_*S1_;
    if (u < B_*S2_) {
      int b = u >> 7, c = u & (S2_-1);
      int sidx = sm.s1[sm.s2[c]];
      const float* src = x + ((size_t)b*N_ + sidx)*3;
      c2[(size_t)u*3+0] = src[0]; c2[(size_t)u*3+1] = src[1]; c2[(size_t)u*3+2] = src[2];
    }
  }
}

// ---- kNN: 2 waves per query (128-thr block), each wave scans half the refs.
//      Wave keeps sorted lowest-64 u64 keys (twiddled-dist<<32 | idx) across
//      lanes; candidates (dd <= Tf, Tf = exact 32nd-smallest dist so far) are
//      wave-compacted into a wave-private LDS ring; every 64 captures one
//      bitonic sort + lowest-64 merge (round-1-verified network) folds them in
//      and tightens Tf. Exact (dist,idx) tie-break end-to-end in u64 domain. ----
#define KNN_KEY(RV, UB)                                                     \
  {                                                                         \
    float dot = qx*(RV).x + qy*(RV).y + qz*(RV).z;                          \
    float dd_ = (qq - 2.0f*dot) + (RV).w;                                   \
    (UB) = __float_as_uint(dd_);                                            \
    (UB) ^= ((unsigned int)((int)(UB) >> 31)) | 0x80000000u;                \
  }

__device__ __forceinline__ void knn_merge64(unsigned long long &lkey,
                                            unsigned long long key, int lane) {
  // full bitonic sort of 'key' across 64 lanes, ascending (round-1-verified)
  #pragma unroll
  for (int k2 = 2; k2 <= 64; k2 <<= 1) {
    #pragma unroll
    for (int j = k2 >> 1; j >= 1; j >>= 1) {
      unsigned long long o = __shfl_xor(key, j);
      bool keepmin = (((lane & j) == 0) == ((lane & k2) == 0));
      if ((o < key) == keepmin) key = o;
    }
  }
  // merge two ascending 64-lists, keep lowest 64 (round-1-verified)
  unsigned long long rev = __shfl(key, 63 - lane);
  unsigned long long v = (lkey < rev) ? lkey : rev;
  #pragma unroll
  for (int j = 32; j >= 1; j >>= 1) {
    unsigned long long o = __shfl_xor(v, j);
    bool keepmin = ((lane & j) == 0);
    if ((o < v) == keepmin) v = o;
  }
  lkey = v;
}

#define KNN_TUPD                                                            \
  {                                                                         \
    unsigned long long k31 = __shfl(lkey, 31);                              \
    unsigned int td = (unsigned int)(k31 >> 32);                            \
    unsigned int msk = ((int)td < 0) ? 0x80000000u : 0xFFFFFFFFu;           \
    Tf = __uint_as_float(td ^ msk);                                         \
  }

#define KNN_CAP(RV, RIDX)                                                   \
  {                                                                         \
    float dot = qx*(RV).x + qy*(RV).y + qz*(RV).z;                          \
    float dd = (qq - 2.0f*dot) + (RV).w;                                    \
    bool cand = (dd <= Tf);                                                 \
    unsigned long long bal = __ballot(cand);                                \
    if (bal) {                                                              \
      if (cand) {                                                           \
        int rank = __builtin_amdgcn_mbcnt_hi((unsigned int)(bal >> 32),     \
                   __builtin_amdgcn_mbcnt_lo((unsigned int)bal, 0));        \
        unsigned int ub = __float_as_uint(dd);                              \
        ub ^= ((unsigned int)((int)ub >> 31)) | 0x80000000u;                \
        cb[ccount + rank] = ((unsigned long long)ub << 32)                  \
                          | (unsigned int)(RIDX);                           \
      }                                                                     \
      ccount += (int)__popcll(bal);                                         \
      if (ccount >= 64) {                                                   \
        unsigned long long key = cb[ccount - 64 + lane];                    \
        knn_merge64(lkey, key, lane);                                       \
        ccount -= 64;                                                       \
        KNN_TUPD;                                                           \
      }                                                                     \
    }                                                                       \
  }

__launch_bounds__(128)
__global__ void k_knn2(const float4* __restrict__ refs4, const float* __restrict__ qpts,
                       int* __restrict__ out_idx, int nrefs, int qshift) {
  __shared__ unsigned long long kbuf[64];
  __shared__ unsigned long long cbuf[2][128];
  const int tid = threadIdx.x, lane = tid & 63, wv = tid >> 6;
  const int q = blockIdx.x;
  const int b = q >> qshift;
  const float4* refs = refs4 + (size_t)b * nrefs;
  const int half = nrefs >> 1;
  const int base = wv * half;
  float qx = qpts[(size_t)q*3+0], qy = qpts[(size_t)q*3+1], qz = qpts[(size_t)q*3+2];
  float qq = qx*qx + qy*qy + qz*qz;
  unsigned long long lkey = ~0ULL;
  float Tf;
  unsigned long long* cb = &cbuf[wv][0];
  int ccount = 0;
  {
    // prologue: sort first 64 refs of this slice into the (all-inf) list
    float4 rv = refs[base + lane];
    unsigned int ub; KNN_KEY(rv, ub);
    unsigned long long key = ((unsigned long long)ub << 32)
                           | (unsigned int)(base + lane);
    knn_merge64(lkey, key, lane);
    KNN_TUPD;
  }
  {
    // refs base+64 .. base+255
    float4 r1 = refs[base + 64 + lane];
    float4 r2 = refs[base + 128 + lane];
    float4 r3 = refs[base + 192 + lane];
    KNN_CAP(r1, base + 64 + lane);
    KNN_CAP(r2, base + 128 + lane);
    KNN_CAP(r3, base + 192 + lane);
  }
  for (int g = base + 256; g + 255 < base + half; g += 256) {
    float4 r0 = refs[g + lane];
    float4 r1 = refs[g + 64 + lane];
    float4 r2 = refs[g + 128 + lane];
    float4 r3 = refs[g + 192 + lane];
    KNN_CAP(r0, g + lane);
    KNN_CAP(r1, g + 64 + lane);
    KNN_CAP(r2, g + 128 + lane);
    KNN_CAP(r3, g + 192 + lane);
  }
  {
    // final partial flush: lanes >= ccount contribute +inf keys
    unsigned long long key = (lane < ccount) ? cb[lane] : ~0ULL;
    knn_merge64(lkey, key, lane);
  }
  // cross-wave exact merge via u64 keys (round-11-verified)
  if (lane < 32) kbuf[wv * 32 + lane] = lkey;
  __syncthreads();
  if (wv == 0) {
    int srcl = (lane < 32) ? lane : (95 - lane);
    unsigned long long v = kbuf[srcl];
    #pragma unroll
    for (int j = 32; j >= 1; j >>= 1) {
      unsigned long long o = __shfl_xor(v, j);
      bool keepmin = ((lane & j) == 0);
      if ((o < v) == keepmin) v = o;
    }
    if (lane < 32) out_idx[(size_t)q*32 + lane] = (int)(v & 0xffffffffu);
  }
}

// ---- SA1 MLP (3->64 relu ->64) + max over 32 neighbors; wave per center.
//      Wave-private LDS broadcast => NO barriers; pipelined neighbor gather. ----
__launch_bounds__(256)
__global__ void k_sa1mlp(const float* __restrict__ x, const int* __restrict__ nidx1,
                         const float* __restrict__ w1, const float* __restrict__ b1,
                         const float* __restrict__ w2, const float* __restrict__ b2,
                         float* __restrict__ f1) {
  __shared__ __align__(16) float hbuf[4][64];
  const int tid = threadIdx.x, wave = tid >> 6, lane = tid & 63;
  const int q = blockIdx.x * 4 + wave;
  const int b = q >> 9;
  const float* xb = x + (size_t)b * N_ * 3;
  float wc0 = w1[lane], wc1 = w1[64 + lane], wc2 = w1[128 + lane];
  float b1v = b1[lane], b2v = b2[lane];
  float w2c[64];
  #pragma unroll
  for (int h = 0; h < 64; ++h) w2c[h] = w2[h*64 + lane];
  const int* nb = nidx1 + (size_t)q * 32;
  int n0 = nb[0];
  float px = xb[3*n0], py = xb[3*n0+1], pz = xb[3*n0+2];
  float fm = -3.402823466e+38f;
  for (int j = 0; j < 32; ++j) {
    int n2 = nb[(j + 1) & 31];
    float nx = xb[3*n2], ny = xb[3*n2+1], nz = xb[3*n2+2];
    float h1 = fmaf(px, wc0, fmaf(py, wc1, fmaf(pz, wc2, b1v)));
    h1 = fmaxf(h1, 0.0f);
    hbuf[wave][lane] = h1;                    // wave-private: no barrier needed
    float acc = b2v;
    const float4* hv = (const float4*)(&hbuf[wave][0]);
    #pragma unroll
    for (int h4 = 0; h4 < 16; ++h4) {
      float4 v = hv[h4];
      acc = fmaf(v.x, w2c[4*h4+0], acc);
      acc = fmaf(v.y, w2c[4*h4+1], acc);
      acc = fmaf(v.z, w2c[4*h4+2], acc);
      acc = fmaf(v.w, w2c[4*h4+3], acc);
    }
    fm = fmaxf(fm, acc);
    px = nx; py = ny; pz = nz;
  }
  f1[(size_t)q*64 + lane] = fm;
}

// ---- SA2 MLP (64->128 relu ->128) + max; block(256) per center, split-K over s ----
__launch_bounds__(256)
__global__ void k_sa2mlp(const float* __restrict__ f1, const int* __restrict__ nidx2,
                         const float* __restrict__ w1, const float* __restrict__ b1,
                         const float* __restrict__ w2, const float* __restrict__ b2,
                         float* __restrict__ f2) {
  __shared__ __align__(16) float fin[64];
  __shared__ __align__(16) float h1s[128];
  __shared__ float ph[128];
  const int tid = threadIdx.x;
  const int s = tid >> 7, t = tid & 127;
  const int q = blockIdx.x;
  const int b = q >> 7;
  float w1r[32], w2r[64];
  #pragma unroll
  for (int i = 0; i < 32; ++i) w1r[i] = w1[(s*32 + i)*128 + t];
  #pragma unroll
  for (int h = 0; h < 64; ++h) w2r[h] = w2[(s*64 + h)*128 + t];
  float b1v = b1[t], b2v = b2[t];
  const int* nb = nidx2 + (size_t)q * 32;
  float fm = -3.402823466e+38f;
  for (int j = 0; j < 32; ++j) {
    int n = nb[j];
    __syncthreads();
    if (tid < 64) fin[tid] = f1[((size_t)b * S1_ + n)*64 + tid];
    __syncthreads();
    float p1 = 0.0f;
    const float4* fv = (const float4*)(fin + s*32);
    #pragma unroll
    for (int i4 = 0; i4 < 8; ++i4) {
      float4 v = fv[i4];
      p1 = fmaf(v.x, w1r[4*i4+0], p1);
      p1 = fmaf(v.y, w1r[4*i4+1], p1);
      p1 = fmaf(v.z, w1r[4*i4+2], p1);
      p1 = fmaf(v.w, w1r[4*i4+3], p1);
    }
    if (s) ph[t] = p1;
    __syncthreads();
    if (!s) h1s[t] = fmaxf(p1 + ph[t] + b1v, 0.0f);
    __syncthreads();
    float p2 = 0.0f;
    const float4* hv = (const float4*)(h1s + s*64);
    #pragma unroll
    for (int h4 = 0; h4 < 16; ++h4) {
      float4 v = hv[h4];
      p2 = fmaf(v.x, w2r[4*h4+0], p2);
      p2 = fmaf(v.y, w2r[4*h4+1], p2);
      p2 = fmaf(v.z, w2r[4*h4+2], p2);
      p2 = fmaf(v.w, w2r[4*h4+3], p2);
    }
    if (s) ph[t] = p2;
    __syncthreads();
    if (!s) fm = fmaxf(fm, p2 + ph[t] + b2v);
  }
  if (!s) f2[(size_t)q*128 + t] = fm;
}

// ---- FP1: kNN-3 over 128 refs + interp + MLP(192->64 relu ->64); wave per query ----
__launch_bounds__(256)
__global__ void k_fp1(const float* __restrict__ c1, const float* __restrict__ c2,
                      const float* __restrict__ f1, const float* __restrict__ f2,
                      const float* __restrict__ w1, const float* __restrict__ b1,
                      const float* __restrict__ w2, const float* __restrict__ b2,
                      float* __restrict__ g1) {
  __shared__ __align__(16) float sw1[192*64];
  __shared__ __align__(16) float sw2[64*64];
  __shared__ __align__(16) float sinp[4][192];
  __shared__ __align__(16) float sh1[4][64];
  __shared__ __align__(16) float4 srefs4[S2_];
  const int tid = threadIdx.x;
  const int wave = tid >> 6, lane = tid & 63;
  const int q = blockIdx.x * 4 + wave;
  const int b = q >> 9;
  for (int i = tid; i < 192*64; i += 256) sw1[i] = w1[i];
  for (int i = tid; i < 64*64; i += 256) sw2[i] = w2[i];
  if (tid < S2_) {
    const float* rp = c2 + ((size_t)b * S2_ + tid) * 3;
    float rx = rp[0], ry = rp[1], rz = rp[2];
    srefs4[tid] = make_float4(rx, ry, rz, rx*rx + ry*ry + rz*rz);
  }
  __syncthreads();
  float qx = c1[(size_t)q*3+0], qy = c1[(size_t)q*3+1], qz = c1[(size_t)q*3+2];
  float qq = qx*qx + qy*qy + qz*qz;
  unsigned long long ka, kb;
  {
    float4 rv = srefs4[lane];
    float dot = qx*rv.x + qy*rv.y + qz*rv.z;
    float d = (qq - 2.0f*dot) + rv.w;
    unsigned int ub = __float_as_uint(d);
    ub ^= ((unsigned int)((int)ub >> 31)) | 0x80000000u;
    ka = ((unsigned long long)ub << 32) | (unsigned int)lane;
    rv = srefs4[lane + 64];
    dot = qx*rv.x + qy*rv.y + qz*rv.z;
    d = (qq - 2.0f*dot) + rv.w;
    ub = __float_as_uint(d);
    ub ^= ((unsigned int)((int)ub >> 31)) | 0x80000000u;
    kb = ((unsigned long long)ub << 32) | (unsigned int)(lane + 64);
    if (kb < ka) { unsigned long long tt = ka; ka = kb; kb = tt; }
  }
  int nsel[3];
  #pragma unroll
  for (int r = 0; r < 3; ++r) {
    unsigned long long m = ka;
    #pragma unroll
    for (int s = 1; s < 64; s <<= 1) {
      unsigned long long o = __shfl_xor(m, s);
      if (o < m) m = o;
    }
    nsel[r] = (int)(m & 0xffffffffu);
    if (ka == m) { ka = kb; kb = ~0ULL; }
  }
  const float* f2b = f2 + (size_t)b * S2_ * 128;
  sinp[wave][lane] = f1[(size_t)q*64 + lane];
  {
    float a0 = f2b[(size_t)nsel[0]*128 + lane];
    float a1 = f2b[(size_t)nsel[1]*128 + lane];
    float a2 = f2b[(size_t)nsel[2]*128 + lane];
    sinp[wave][64 + lane] = (a0 + a1 + a2) / 3.0f;
    a0 = f2b[(size_t)nsel[0]*128 + 64 + lane];
    a1 = f2b[(size_t)nsel[1]*128 + 64 + lane];
    a2 = f2b[(size_t)nsel[2]*128 + 64 + lane];
    sinp[wave][128 + lane] = (a0 + a1 + a2) / 3.0f;
  }
  __syncthreads();
  float acc = b1[lane];
  const float4* sv = (const float4*)(&sinp[wave][0]);
  #pragma unroll
  for (int i4 = 0; i4 < 48; ++i4) {
    float4 v = sv[i4];
    acc = fmaf(v.x, sw1[(4*i4+0)*64 + lane], acc);
    acc = fmaf(v.y, sw1[(4*i4+1)*64 + lane], acc);
    acc = fmaf(v.z, sw1[(4*i4+2)*64 + lane], acc);
    acc = fmaf(v.w, sw1[(4*i4+3)*64 + lane], acc);
  }
  sh1[wave][lane] = fmaxf(acc, 0.0f);
  __syncthreads();
  float acc2 = b2[lane];
  const float4* hv = (const float4*)(&sh1[wave][0]);
  #pragma unroll
  for (int h4 = 0; h4 < 16; ++h4) {
    float4 v = hv[h4];
    acc2 = fmaf(v.x, sw2[(4*h4+0)*64 + lane], acc2);
    acc2 = fmaf(v.y, sw2[(4*h4+1)*64 + lane], acc2);
    acc2 = fmaf(v.z, sw2[(4*h4+2)*64 + lane], acc2);
    acc2 = fmaf(v.w, sw2[(4*h4+3)*64 + lane], acc2);
  }
  g1[(size_t)q*64 + lane] = acc2;
}

// ---- FP2: kNN-3 over 512 refs + interp + MLP(67->32 relu ->32) + FC + log_softmax ----
// Scan streams refs from GLOBAL c1r4 (wave-uniform addr, L1-resident); interp
// folded into w1 loop (no fi[64]); *(1/3) instead of fdiv.
#define FP2_PROC(RV, R)                                                     \
  {                                                                         \
    float dot = qx*(RV).x + qy*(RV).y + qz*(RV).z;                          \
    float dd = (qq - 2.0f*dot) + (RV).w;                                    \
    bool c0 = dd < d0, c1 = dd < d1, c2 = dd < d2;                          \
    i2 = c1 ? i1 : (c2 ? (R) : i2);                                         \
    d2 = c1 ? d1 : fminf(d2, dd);                                           \
    i1 = c0 ? i0 : (c1 ? (R) : i1);                                         \
    d1 = c0 ? d0 : fminf(d1, dd);                                           \
    i0 = c0 ? (R) : i0;                                                     \
    d0 = fminf(d0, dd);                                                     \
  }

__launch_bounds__(256)
__global__ void k_fp2(const float* __restrict__ x, const float4* __restrict__ c1r4,
                      const float* __restrict__ g1,
                      const float* __restrict__ w1, const float* __restrict__ b1,
                      const float* __restrict__ w2, const float* __restrict__ b2,
                      const float* __restrict__ fcw, const float* __restrict__ fcb,
                      float* __restrict__ out) {
  __shared__ __align__(16) float sw1[67*32];
  __shared__ __align__(16) float sw2[32*32];
  __shared__ __align__(16) float sfc[64];
  __shared__ float sb1[32], sb2[32], sfcb[2];
  const int tid = threadIdx.x;
  const int b = blockIdx.x >> 7;
  const int n = ((blockIdx.x & 127) << 8) + tid;
  for (int i = tid; i < 67*32; i += 256) sw1[i] = w1[i];
  for (int i = tid; i < 32*32; i += 256) sw2[i] = w2[i];
  if (tid < 64) sfc[tid] = fcw[tid];
  if (tid < 32) { sb1[tid] = b1[tid]; sb2[tid] = b2[tid]; }
  if (tid < 2) sfcb[tid] = fcb[tid];
  __syncthreads();
  const float* xb = x + (size_t)b * N_ * 3;
  float qx = xb[3*n], qy = xb[3*n+1], qz = xb[3*n+2];
  float qq = qx*qx + qy*qy + qz*qz;
  const float4* refs = c1r4 + (size_t)b * S1_;
  float d0 = 3.402823466e+38f, d1 = d0, d2 = d0;
  int i0 = 0, i1 = 0, i2 = 0;
  for (int r = 0; r < S1_; r += 4) {
    float4 ra = refs[r+0];
    float4 rb = refs[r+1];
    float4 rc = refs[r+2];
    float4 rd = refs[r+3];
    FP2_PROC(ra, r+0);
    FP2_PROC(rb, r+1);
    FP2_PROC(rc, r+2);
    FP2_PROC(rd, r+3);
  }
  const float* g1b = g1 + (size_t)b * S1_ * 64;
  const float4* p0 = (const float4*)(g1b + (size_t)i0 * 64);
  const float4* p1 = (const float4*)(g1b + (size_t)i1 * 64);
  const float4* p2 = (const float4*)(g1b + (size_t)i2 * 64);
  const float THIRD = 1.0f / 3.0f;
  float h1r[32];
  #pragma unroll
  for (int k = 0; k < 32; ++k) h1r[k] = sb1[k];
  // rows 0..2: query coords
  #pragma unroll
  for (int i = 0; i < 3; ++i) {
    float v = (i == 0) ? qx : (i == 1) ? qy : qz;
    const float4* wrow = (const float4*)(sw1 + i*32);
    #pragma unroll
    for (int kq = 0; kq < 8; ++kq) {
      float4 wv = wrow[kq];
      h1r[4*kq+0] = fmaf(v, wv.x, h1r[4*kq+0]);
      h1r[4*kq+1] = fmaf(v, wv.y, h1r[4*kq+1]);
      h1r[4*kq+2] = fmaf(v, wv.z, h1r[4*kq+2]);
      h1r[4*kq+3] = fmaf(v, wv.w, h1r[4*kq+3]);
    }
  }
  // rows 3..66: interpolated features computed on the fly (no fi[64] array)
  #pragma unroll 4
  for (int o = 0; o < 16; ++o) {
    float4 a = p0[o], bq = p1[o], cq = p2[o];
    float vv[4];
    vv[0] = (a.x + bq.x + cq.x) * THIRD;
    vv[1] = (a.y + bq.y + cq.y) * THIRD;
    vv[2] = (a.z + bq.z + cq.z) * THIRD;
    vv[3] = (a.w + bq.w + cq.w) * THIRD;
    #pragma unroll
    for (int j = 0; j < 4; ++j) {
      float v = vv[j];
      const float4* wrow = (const float4*)(sw1 + (3 + 4*o + j)*32);
      #pragma unroll
      for (int kq = 0; kq < 8; ++kq) {
        float4 wv = wrow[kq];
        h1r[4*kq+0] = fmaf(v, wv.x, h1r[4*kq+0]);
        h1r[4*kq+1] = fmaf(v, wv.y, h1r[4*kq+1]);
        h1r[4*kq+2] = fmaf(v, wv.z, h1r[4*kq+2]);
        h1r[4*kq+3] = fmaf(v, wv.w, h1r[4*kq+3]);
      }
    }
  }
  #pragma unroll
  for (int k = 0; k < 32; ++k) h1r[k] = fmaxf(h1r[k], 0.0f);
  float h2r[32];
  #pragma unroll
  for (int m = 0; m < 32; ++m) h2r[m] = sb2[m];
  #pragma unroll
  for (int k = 0; k < 32; ++k) {
    float v = h1r[k];
    const float4* wrow = (const float4*)(sw2 + k*32);
    #pragma unroll
    for (int mq = 0; mq < 8; ++mq) {
      float4 wv = wrow[mq];
      h2r[4*mq+0] = fmaf(v, wv.x, h2r[4*mq+0]);
      h2r[4*mq+1] = fmaf(v, wv.y, h2r[4*mq+1]);
      h2r[4*mq+2] = fmaf(v, wv.z, h2r[4*mq+2]);
      h2r[4*mq+3] = fmaf(v, wv.w, h2r[4*mq+3]);
    }
  }
  float l0 = sfcb[0], l1 = sfcb[1];
  #pragma unroll
  for (int m = 0; m < 32; ++m) {
    l0 = fmaf(h2r[m], sfc[2*m+0], l0);
    l1 = fmaf(h2r[m], sfc[2*m+1], l1);
  }
  float mx = fmaxf(l0, l1);
  float s0 = l0 - mx, s1 = l1 - mx;
  float lg = logf(expf(s0) + expf(s1));
  float2 res; res.x = s0 - lg; res.y = s1 - lg;
  ((float2*)out)[(size_t)b * N_ + n] = res;
}

// ================= launch =================
extern "C" void kernel_launch(void* const* d_in, const int* in_sizes, int n_in,
                              void* d_out, int out_size, void* d_ws, size_t ws_size,
                              hipStream_t stream) {
  (void)in_sizes; (void)n_in; (void)out_size; (void)ws_size;
  const float* x     = (const float*)d_in[0];
  const float* sa1w1 = (const float*)d_in[1];
  const float* sa1b1 = (const float*)d_in[2];
  const float* sa1w2 = (const float*)d_in[3];
  const float* sa1b2 = (const float*)d_in[4];
  const float* sa2w1 = (const float*)d_in[5];
  const float* sa2b1 = (const float*)d_in[6];
  const float* sa2w2 = (const float*)d_in[7];
  const float* sa2b2 = (const float*)d_in[8];
  const float* fp1w1 = (const float*)d_in[9];
  const float* fp1b1 = (const float*)d_in[10];
  const float* fp1w2 = (const float*)d_in[11];
  const float* fp1b2 = (const float*)d_in[12];
  const float* fp2w1 = (const float*)d_in[13];
  const float* fp2b1 = (const float*)d_in[14];
  const float* fp2w2 = (const float*)d_in[15];
  const float* fp2b2 = (const float*)d_in[16];
  const float* fcw   = (const float*)d_in[17];
  const float* fcb   = (const float*)d_in[18];
  float* out = (float*)d_out;
  char* ws = (char*)d_ws;
  float4* xr4  = (float4*)(ws + OFF_XR4);
  float*  c1   = (float*)(ws + OFF_C1);
  float4* c1r4 = (float4*)(ws + OFF_C1R4);
  float*  c2   = (float*)(ws + OFF_C2);
  int*    nidx1= (int*)(ws + OFF_NIDX1);
  float*  f1   = (float*)(ws + OFF_F1);
  int*    nidx2= (int*)(ws + OFF_NIDX2);
  float*  f2   = (float*)(ws + OFF_F2);
  float*  g1   = (float*)(ws + OFF_G1);

  Samps smp;
  compute_samples(smp.s1, smp.s2);

  hipLaunchKernelGGL(k_prep,    dim3(B_*N_/256), dim3(256), 0, stream, x, xr4);
  hipLaunchKernelGGL(k_centers, dim3((B_*(S1_+S2_)+255)/256), dim3(256), 0, stream,
                     x, smp, c1, c1r4, c2);
  hipLaunchKernelGGL(k_knn2,    dim3(B_*S1_), dim3(128), 0, stream, xr4, c1, nidx1, N_, 9);
  hipLaunchKernelGGL(k_sa1mlp,  dim3(B_*S1_/4), dim3(256), 0, stream,
                     x, nidx1, sa1w1, sa1b1, sa1w2, sa1b2, f1);
  hipLaunchKernelGGL(k_knn2,    dim3(B_*S2_), dim3(128), 0, stream, c1r4, c2, nidx2, S1_, 7);
  hipLaunchKernelGGL(k_sa2mlp,  dim3(B_*S2_), dim3(256), 0, stream,
                     f1, nidx2, sa2w1, sa2b1, sa2w2, sa2b2, f2);
  hipLaunchKernelGGL(k_fp1,     dim3(B_*S1_/4), dim3(256), 0, stream,
                     c1, c2, f1, f2, fp1w1, fp1b1, fp1w2, fp1b2, g1);
  hipLaunchKernelGGL(k_fp2,     dim3(B_*N_/256), dim3(256), 0, stream,
                     x, c1r4, g1, fp2w1, fp2b1, fp2w2, fp2b2, fcw, fcb, out);
}